// Round 1
// baseline (605.091 us; speedup 1.0000x reference)
//
#include <hip/hip_runtime.h>
#include <hip/hip_bf16.h>

#define N_TOK 16384
#define C_DIM 256
#define E_NUM 8
#define H_DIM 682
#define H_PAD 704          // 22 * 32
#define NROWS (N_TOK * 2)  // total expert-assignments (top-2)

typedef short short8 __attribute__((ext_vector_type(8)));
typedef float floatx4 __attribute__((ext_vector_type(4)));

__device__ inline unsigned short f2bf(float v) {
    union { float f; unsigned int u; } x; x.f = v;
    unsigned int r = (x.u + 0x7fffu + ((x.u >> 16) & 1u)) >> 16;
    return (unsigned short)r;
}

// Generic fp32 -> bf16 convert with zero padding. dst is [mats][Rd][Cd],
// src is [mats][Rs][Cs]; pad region (r>=Rs || c>=Cs) written as 0.
__global__ void convert_pad(const float* __restrict__ src, unsigned short* __restrict__ dst,
                            int Rs, int Rd, int Cs, int Cd, int total) {
    int idx = blockIdx.x * blockDim.x + threadIdx.x;
    if (idx >= total) return;
    int per = Rd * Cd;
    int e = idx / per;
    int rem = idx - e * per;
    int r = rem / Cd;
    int c = rem - r * Cd;
    float v = (r < Rs && c < Cs) ? src[((size_t)e * Rs + r) * Cs + c] : 0.0f;
    dst[idx] = f2bf(v);
}

// fp32 router: one wave per token. logits -> softmax -> top2 -> renorm gates.
__global__ __launch_bounds__(256) void router_kernel(
    const float* __restrict__ x, const float* __restrict__ rw,
    int* __restrict__ counts, int* __restrict__ as_e, int* __restrict__ as_slot,
    float* __restrict__ as_gate) {
    __shared__ float rws[E_NUM * C_DIM];
    int tid = threadIdx.x;
    for (int i = tid; i < E_NUM * C_DIM; i += 256) rws[i] = rw[i];
    __syncthreads();
    int wave = tid >> 6, lane = tid & 63;
    int t = blockIdx.x * 4 + wave;
    const float4 xv = *(const float4*)(x + (size_t)t * C_DIM + lane * 4);
    float p[E_NUM];
#pragma unroll
    for (int e = 0; e < E_NUM; e++) {
        const float* wr = &rws[e * C_DIM + lane * 4];
        p[e] = xv.x * wr[0] + xv.y * wr[1] + xv.z * wr[2] + xv.w * wr[3];
    }
#pragma unroll
    for (int off = 32; off >= 1; off >>= 1) {
#pragma unroll
        for (int e = 0; e < E_NUM; e++) p[e] += __shfl_down(p[e], off, 64);
    }
    if (lane == 0) {
        float m = p[0];
#pragma unroll
        for (int e = 1; e < E_NUM; e++) m = fmaxf(m, p[e]);
        float s = 0.f, q[E_NUM];
#pragma unroll
        for (int e = 0; e < E_NUM; e++) { q[e] = expf(p[e] - m); s += q[e]; }
#pragma unroll
        for (int e = 0; e < E_NUM; e++) q[e] /= s;
        int e0 = 0;
#pragma unroll
        for (int e = 1; e < E_NUM; e++) if (q[e] > q[e0]) e0 = e;
        int e1 = (e0 == 0) ? 1 : 0;
#pragma unroll
        for (int e = 0; e < E_NUM; e++) {
            if (e != e0 && q[e] > q[e1]) e1 = e;
        }
        float g0 = q[e0], g1 = q[e1];
        float denom = g0 + g1 + 1e-9f;
        g0 /= denom; g1 /= denom;
        int s0 = atomicAdd(&counts[e0], 1);
        int s1 = atomicAdd(&counts[e1], 1);
        as_e[t * 2] = e0; as_slot[t * 2] = s0; as_gate[t * 2] = g0;
        as_e[t * 2 + 1] = e1; as_slot[t * 2 + 1] = s1; as_gate[t * 2 + 1] = g1;
    }
}

__global__ void scan_kernel(const int* __restrict__ counts, int* __restrict__ offsets) {
    if (threadIdx.x == 0 && blockIdx.x == 0) {
        int acc = 0;
        for (int e = 0; e < E_NUM; e++) { offsets[e] = acc; acc += counts[e]; }
        offsets[E_NUM] = acc;
    }
}

__global__ void scatter_kernel(const int* __restrict__ as_e, const int* __restrict__ as_slot,
                               const float* __restrict__ as_gate, const int* __restrict__ offsets,
                               int* __restrict__ row_token, float* __restrict__ row_gate) {
    int a = blockIdx.x * blockDim.x + threadIdx.x;
    if (a >= NROWS) return;
    int row = offsets[as_e[a]] + as_slot[a];
    row_token[row] = a >> 1;
    row_gate[row] = as_gate[a];
}

#define BM 128
#define BN 64
#define BK 32

// Pass 1: h[row][0..H_PAD) = silu(x_row . w1_e^T) * (x_row . w3_e^T), bf16.
__global__ __launch_bounds__(256, 2) void expert_ffn1(
    const unsigned short* __restrict__ xb, const unsigned short* __restrict__ w1b,
    const unsigned short* __restrict__ w3b, const int* __restrict__ offsets,
    const int* __restrict__ row_token, unsigned short* __restrict__ h) {
    int e = blockIdx.x >> 7;
    int mt = blockIdx.x & 127;
    int nt = blockIdx.y;  // 0..10
    int off0 = offsets[e], off1 = offsets[e + 1];
    int row0 = off0 + mt * BM;
    if (row0 >= off1) return;
    int mval = min(BM, off1 - row0);

    __shared__ unsigned short As[BM][BK];
    __shared__ unsigned short B1s[BN][BK];
    __shared__ unsigned short B3s[BN][BK];
    __shared__ unsigned short Hs[BM][BN + 8];  // +8 shorts: 144B stride, 16B-aligned rows

    int tid = threadIdx.x;
    int lane = tid & 63, w = tid >> 6;
    int arow = tid >> 2;            // 0..63
    int acol = (tid & 3) * 8;       // 16B chunks
    int tok0 = (arow < mval) ? row_token[row0 + arow] : -1;
    int tok1 = (arow + 64 < mval) ? row_token[row0 + arow + 64] : -1;
    const unsigned short* a0p = (tok0 >= 0) ? xb + (size_t)tok0 * C_DIM + acol : nullptr;
    const unsigned short* a1p = (tok1 >= 0) ? xb + (size_t)tok1 * C_DIM + acol : nullptr;
    int ng = nt * BN + arow;  // < 704 always
    const unsigned short* b1p = w1b + ((size_t)e * H_PAD + ng) * C_DIM + acol;
    const unsigned short* b3p = w3b + ((size_t)e * H_PAD + ng) * C_DIM + acol;

    floatx4 acc1[2][4], acc3[2][4];
#pragma unroll
    for (int m = 0; m < 2; m++)
#pragma unroll
        for (int n = 0; n < 4; n++) {
            acc1[m][n] = (floatx4){0.f, 0.f, 0.f, 0.f};
            acc3[m][n] = (floatx4){0.f, 0.f, 0.f, 0.f};
        }

    int mrow = w * 32 + (lane & 15);
    int ko = (lane >> 4) * 8;
    const int4 z4 = {0, 0, 0, 0};
    for (int kt = 0; kt < C_DIM / BK; kt++) {
        int kb = kt * BK;
        *(int4*)&As[arow][acol] = a0p ? *(const int4*)(a0p + kb) : z4;
        *(int4*)&As[arow + 64][acol] = a1p ? *(const int4*)(a1p + kb) : z4;
        *(int4*)&B1s[arow][acol] = *(const int4*)(b1p + kb);
        *(int4*)&B3s[arow][acol] = *(const int4*)(b3p + kb);
        __syncthreads();
        short8 a0 = *(short8*)&As[mrow][ko];
        short8 a1 = *(short8*)&As[mrow + 16][ko];
#pragma unroll
        for (int n = 0; n < 4; n++) {
            short8 b1 = *(short8*)&B1s[n * 16 + (lane & 15)][ko];
            short8 b3 = *(short8*)&B3s[n * 16 + (lane & 15)][ko];
            acc1[0][n] = __builtin_amdgcn_mfma_f32_16x16x32_bf16(a0, b1, acc1[0][n], 0, 0, 0);
            acc1[1][n] = __builtin_amdgcn_mfma_f32_16x16x32_bf16(a1, b1, acc1[1][n], 0, 0, 0);
            acc3[0][n] = __builtin_amdgcn_mfma_f32_16x16x32_bf16(a0, b3, acc3[0][n], 0, 0, 0);
            acc3[1][n] = __builtin_amdgcn_mfma_f32_16x16x32_bf16(a1, b3, acc3[1][n], 0, 0, 0);
        }
        __syncthreads();
    }

    int quad = lane >> 4;
#pragma unroll
    for (int m = 0; m < 2; m++)
#pragma unroll
        for (int n = 0; n < 4; n++)
#pragma unroll
            for (int r = 0; r < 4; r++) {
                float h1 = acc1[m][n][r], h3 = acc3[m][n][r];
                float sv = h1 / (1.0f + __expf(-h1)) * h3;
                Hs[w * 32 + m * 16 + quad * 4 + r][n * 16 + (lane & 15)] = f2bf(sv);
            }
    __syncthreads();
    int srow = tid >> 3;            // 0..31
    int scol = (tid & 7) * 8;
#pragma unroll
    for (int it = 0; it < 4; it++) {
        int rr = srow + it * 32;
        if (rr < mval)
            *(int4*)(h + (size_t)(row0 + rr) * H_PAD + nt * BN + scol) = *(int4*)&Hs[rr][scol];
    }
}

// Pass 2: y = h . w2_e^T; out[token] += gate * y (atomic).
__global__ __launch_bounds__(256, 2) void expert_ffn2(
    const unsigned short* __restrict__ h, const unsigned short* __restrict__ w2b,
    const int* __restrict__ offsets, const int* __restrict__ row_token,
    const float* __restrict__ row_gate, float* __restrict__ out) {
    int e = blockIdx.x >> 7;
    int mt = blockIdx.x & 127;
    int nt = blockIdx.y;  // 0..3
    int off0 = offsets[e], off1 = offsets[e + 1];
    int row0 = off0 + mt * BM;
    if (row0 >= off1) return;
    int mval = min(BM, off1 - row0);

    __shared__ unsigned short As[BM][BK];
    __shared__ unsigned short Bs[BN][BK];

    int tid = threadIdx.x, lane = tid & 63, w = tid >> 6;
    int arow = tid >> 2;
    int acol = (tid & 3) * 8;
    int r0 = min(row0 + arow, NROWS - 1);
    int r1 = min(row0 + arow + 64, NROWS - 1);
    const unsigned short* a0p = h + (size_t)r0 * H_PAD + acol;
    const unsigned short* a1p = h + (size_t)r1 * H_PAD + acol;
    int cg = nt * BN + arow;  // < 256
    const unsigned short* bp = w2b + ((size_t)e * C_DIM + cg) * H_PAD + acol;

    floatx4 acc[2][4];
#pragma unroll
    for (int m = 0; m < 2; m++)
#pragma unroll
        for (int n = 0; n < 4; n++) acc[m][n] = (floatx4){0.f, 0.f, 0.f, 0.f};

    int mrow = w * 32 + (lane & 15);
    int ko = (lane >> 4) * 8;
    for (int kt = 0; kt < H_PAD / BK; kt++) {  // 22 steps
        int kb = kt * BK;
        *(int4*)&As[arow][acol] = *(const int4*)(a0p + kb);
        *(int4*)&As[arow + 64][acol] = *(const int4*)(a1p + kb);
        *(int4*)&Bs[arow][acol] = *(const int4*)(bp + kb);
        __syncthreads();
        short8 a0 = *(short8*)&As[mrow][ko];
        short8 a1 = *(short8*)&As[mrow + 16][ko];
#pragma unroll
        for (int n = 0; n < 4; n++) {
            short8 b = *(short8*)&Bs[n * 16 + (lane & 15)][ko];
            acc[0][n] = __builtin_amdgcn_mfma_f32_16x16x32_bf16(a0, b, acc[0][n], 0, 0, 0);
            acc[1][n] = __builtin_amdgcn_mfma_f32_16x16x32_bf16(a1, b, acc[1][n], 0, 0, 0);
        }
        __syncthreads();
    }

    int quad = lane >> 4;
#pragma unroll
    for (int m = 0; m < 2; m++) {
#pragma unroll
        for (int r = 0; r < 4; r++) {
            int rl = w * 32 + m * 16 + quad * 4 + r;
            if (rl < mval) {
                int row = row0 + rl;
                int token = row_token[row];
                float g = row_gate[row];
                float* op = out + (size_t)token * C_DIM + nt * BN + (lane & 15);
#pragma unroll
                for (int n = 0; n < 4; n++) atomicAdd(op + n * 16, g * acc[m][n][r]);
            }
        }
    }
}

extern "C" void kernel_launch(void* const* d_in, const int* in_sizes, int n_in,
                              void* d_out, int out_size, void* d_ws, size_t ws_size,
                              hipStream_t stream) {
    const float* x = (const float*)d_in[0];
    const float* rw = (const float*)d_in[1];
    const float* w1 = (const float*)d_in[2];
    const float* w2 = (const float*)d_in[3];
    const float* w3 = (const float*)d_in[4];
    float* out = (float*)d_out;

    char* ws = (char*)d_ws;
    size_t o = 0;
    auto alloc = [&](size_t bytes) {
        void* p = ws + o;
        o = (o + bytes + 255) & ~(size_t)255;
        return p;
    };
    unsigned short* xb = (unsigned short*)alloc((size_t)N_TOK * C_DIM * 2);
    unsigned short* w1b = (unsigned short*)alloc((size_t)E_NUM * H_PAD * C_DIM * 2);
    unsigned short* w3b = (unsigned short*)alloc((size_t)E_NUM * H_PAD * C_DIM * 2);
    unsigned short* w2b = (unsigned short*)alloc((size_t)E_NUM * C_DIM * H_PAD * 2);
    unsigned short* hbuf = (unsigned short*)alloc((size_t)NROWS * H_PAD * 2);
    int* counts = (int*)alloc(E_NUM * 4);
    int* offsets = (int*)alloc((E_NUM + 1) * 4);
    int* as_e = (int*)alloc(NROWS * 4);
    int* as_slot = (int*)alloc(NROWS * 4);
    float* as_gate = (float*)alloc(NROWS * 4);
    int* row_token = (int*)alloc(NROWS * 4);
    float* row_gate = (float*)alloc(NROWS * 4);

    hipMemsetAsync(counts, 0, E_NUM * 4, stream);
    hipMemsetAsync(out, 0, (size_t)N_TOK * C_DIM * 4, stream);

    int tx = N_TOK * C_DIM;
    convert_pad<<<(tx + 255) / 256, 256, 0, stream>>>(x, xb, N_TOK, N_TOK, C_DIM, C_DIM, tx);
    int tw13 = E_NUM * H_PAD * C_DIM;
    convert_pad<<<(tw13 + 255) / 256, 256, 0, stream>>>(w1, w1b, H_DIM, H_PAD, C_DIM, C_DIM, tw13);
    convert_pad<<<(tw13 + 255) / 256, 256, 0, stream>>>(w3, w3b, H_DIM, H_PAD, C_DIM, C_DIM, tw13);
    int tw2 = E_NUM * C_DIM * H_PAD;
    convert_pad<<<(tw2 + 255) / 256, 256, 0, stream>>>(w2, w2b, C_DIM, C_DIM, H_DIM, H_PAD, tw2);

    router_kernel<<<N_TOK / 4, 256, 0, stream>>>(x, rw, counts, as_e, as_slot, as_gate);
    scan_kernel<<<1, 64, 0, stream>>>(counts, offsets);
    scatter_kernel<<<NROWS / 256, 256, 0, stream>>>(as_e, as_slot, as_gate, offsets, row_token, row_gate);

    expert_ffn1<<<dim3(E_NUM * 128, H_PAD / BN), 256, 0, stream>>>(xb, w1b, w3b, offsets, row_token, hbuf);
    expert_ffn2<<<dim3(E_NUM * 128, C_DIM / BN), 256, 0, stream>>>(hbuf, w2b, offsets, row_token, row_gate, out);
}

// Round 2
// 303.648 us; speedup vs baseline: 1.9927x; 1.9927x over previous
//
#include <hip/hip_runtime.h>
#include <hip/hip_bf16.h>

#define N_TOK 16384
#define C_DIM 256
#define E_NUM 8
#define H_DIM 682
#define H_PAD 704          // 22 * 32
#define NROWS (N_TOK * 2)  // total expert-assignments (top-2)

typedef short short8 __attribute__((ext_vector_type(8)));
typedef float floatx4 __attribute__((ext_vector_type(4)));

__device__ inline unsigned short f2bf(float v) {
    union { float f; unsigned int u; } x; x.f = v;
    unsigned int r = (x.u + 0x7fffu + ((x.u >> 16) & 1u)) >> 16;
    return (unsigned short)r;
}

// Generic fp32 -> bf16 convert with zero padding. dst is [mats][Rd][Cd],
// src is [mats][Rs][Cs]; pad region (r>=Rs || c>=Cs) written as 0.
__global__ void convert_pad(const float* __restrict__ src, unsigned short* __restrict__ dst,
                            int Rs, int Rd, int Cs, int Cd, int total) {
    int idx = blockIdx.x * blockDim.x + threadIdx.x;
    if (idx >= total) return;
    int per = Rd * Cd;
    int e = idx / per;
    int rem = idx - e * per;
    int r = rem / Cd;
    int c = rem - r * Cd;
    float v = (r < Rs && c < Cs) ? src[((size_t)e * Rs + r) * Cs + c] : 0.0f;
    dst[idx] = f2bf(v);
}

// fp32 router: one wave per token. logits -> softmax -> top2 -> renorm gates.
// NO atomics: just writes per-assignment expert id + gate. Binning happens in
// bin_kernel (deterministic, single block).
__global__ __launch_bounds__(256) void router_kernel(
    const float* __restrict__ x, const float* __restrict__ rw,
    int* __restrict__ as_e, float* __restrict__ as_gate) {
    __shared__ float rws[E_NUM * C_DIM];
    int tid = threadIdx.x;
    for (int i = tid; i < E_NUM * C_DIM; i += 256) rws[i] = rw[i];
    __syncthreads();
    int wave = tid >> 6, lane = tid & 63;
    int t = blockIdx.x * 4 + wave;
    const float4 xv = *(const float4*)(x + (size_t)t * C_DIM + lane * 4);
    float p[E_NUM];
#pragma unroll
    for (int e = 0; e < E_NUM; e++) {
        const float* wr = &rws[e * C_DIM + lane * 4];
        p[e] = xv.x * wr[0] + xv.y * wr[1] + xv.z * wr[2] + xv.w * wr[3];
    }
#pragma unroll
    for (int off = 32; off >= 1; off >>= 1) {
#pragma unroll
        for (int e = 0; e < E_NUM; e++) p[e] += __shfl_down(p[e], off, 64);
    }
    if (lane == 0) {
        float m = p[0];
#pragma unroll
        for (int e = 1; e < E_NUM; e++) m = fmaxf(m, p[e]);
        float s = 0.f, q[E_NUM];
#pragma unroll
        for (int e = 0; e < E_NUM; e++) { q[e] = expf(p[e] - m); s += q[e]; }
#pragma unroll
        for (int e = 0; e < E_NUM; e++) q[e] /= s;
        int e0 = 0;
#pragma unroll
        for (int e = 1; e < E_NUM; e++) if (q[e] > q[e0]) e0 = e;
        int e1 = (e0 == 0) ? 1 : 0;
#pragma unroll
        for (int e = 0; e < E_NUM; e++) {
            if (e != e0 && q[e] > q[e1]) e1 = e;
        }
        float g0 = q[e0], g1 = q[e1];
        float denom = g0 + g1 + 1e-9f;
        g0 /= denom; g1 /= denom;
        as_e[t * 2] = e0; as_gate[t * 2] = g0;
        as_e[t * 2 + 1] = e1; as_gate[t * 2 + 1] = g1;
    }
}

// Deterministic binning: one block, 256 threads, 128 assignments each.
// Per-thread histogram -> stable exclusive scan (e-major, thread-minor) ->
// scatter row_token/row_gate sorted by expert; also writes offsets[9].
__global__ __launch_bounds__(256) void bin_kernel(
    const int* __restrict__ as_e, const float* __restrict__ as_gate,
    int* __restrict__ offsets, int* __restrict__ row_token, float* __restrict__ row_gate) {
    __shared__ int hist[256][E_NUM];
    __shared__ int start[256][E_NUM];
    int tid = threadIdx.x;
    int base = tid * (NROWS / 256);  // 128 per thread
    int h[E_NUM];
#pragma unroll
    for (int e = 0; e < E_NUM; e++) h[e] = 0;
    int le[NROWS / 256];
    for (int i = 0; i < NROWS / 256; i++) {
        int e = as_e[base + i];
        le[i] = e;
        h[e]++;
    }
#pragma unroll
    for (int e = 0; e < E_NUM; e++) hist[tid][e] = h[e];
    __syncthreads();
    if (tid == 0) {
        int acc = 0;
        for (int e = 0; e < E_NUM; e++) {
            offsets[e] = acc;
            for (int t = 0; t < 256; t++) { start[t][e] = acc; acc += hist[t][e]; }
        }
        offsets[E_NUM] = acc;
    }
    __syncthreads();
    int pos[E_NUM];
#pragma unroll
    for (int e = 0; e < E_NUM; e++) pos[e] = start[tid][e];
    for (int i = 0; i < NROWS / 256; i++) {
        int a = base + i;
        int e = le[i];
        int row = pos[e]++;
        row_token[row] = a >> 1;
        row_gate[row] = as_gate[a];
    }
}

#define BM 128
#define BN 64
#define BK 32

// Pass 1: h[row][0..H_PAD) = silu(x_row . w1_e^T) * (x_row . w3_e^T), bf16.
__global__ __launch_bounds__(256, 2) void expert_ffn1(
    const unsigned short* __restrict__ xb, const unsigned short* __restrict__ w1b,
    const unsigned short* __restrict__ w3b, const int* __restrict__ offsets,
    const int* __restrict__ row_token, unsigned short* __restrict__ h) {
    int e = blockIdx.x >> 7;
    int mt = blockIdx.x & 127;
    int nt = blockIdx.y;  // 0..10
    int off0 = offsets[e], off1 = offsets[e + 1];
    int row0 = off0 + mt * BM;
    if (row0 >= off1) return;
    int mval = min(BM, off1 - row0);

    __shared__ unsigned short As[BM][BK];
    __shared__ unsigned short B1s[BN][BK];
    __shared__ unsigned short B3s[BN][BK];
    __shared__ unsigned short Hs[BM][BN + 8];  // +8 shorts: 144B stride, 16B-aligned rows

    int tid = threadIdx.x;
    int lane = tid & 63, w = tid >> 6;
    int arow = tid >> 2;            // 0..63
    int acol = (tid & 3) * 8;       // 16B chunks
    int tok0 = (arow < mval) ? row_token[row0 + arow] : -1;
    int tok1 = (arow + 64 < mval) ? row_token[row0 + arow + 64] : -1;
    const unsigned short* a0p = (tok0 >= 0) ? xb + (size_t)tok0 * C_DIM + acol : nullptr;
    const unsigned short* a1p = (tok1 >= 0) ? xb + (size_t)tok1 * C_DIM + acol : nullptr;
    int ng = nt * BN + arow;  // < 704 always
    const unsigned short* b1p = w1b + ((size_t)e * H_PAD + ng) * C_DIM + acol;
    const unsigned short* b3p = w3b + ((size_t)e * H_PAD + ng) * C_DIM + acol;

    floatx4 acc1[2][4], acc3[2][4];
#pragma unroll
    for (int m = 0; m < 2; m++)
#pragma unroll
        for (int n = 0; n < 4; n++) {
            acc1[m][n] = (floatx4){0.f, 0.f, 0.f, 0.f};
            acc3[m][n] = (floatx4){0.f, 0.f, 0.f, 0.f};
        }

    int mrow = w * 32 + (lane & 15);
    int ko = (lane >> 4) * 8;
    const int4 z4 = {0, 0, 0, 0};
    for (int kt = 0; kt < C_DIM / BK; kt++) {
        int kb = kt * BK;
        *(int4*)&As[arow][acol] = a0p ? *(const int4*)(a0p + kb) : z4;
        *(int4*)&As[arow + 64][acol] = a1p ? *(const int4*)(a1p + kb) : z4;
        *(int4*)&B1s[arow][acol] = *(const int4*)(b1p + kb);
        *(int4*)&B3s[arow][acol] = *(const int4*)(b3p + kb);
        __syncthreads();
        short8 a0 = *(short8*)&As[mrow][ko];
        short8 a1 = *(short8*)&As[mrow + 16][ko];
#pragma unroll
        for (int n = 0; n < 4; n++) {
            short8 b1 = *(short8*)&B1s[n * 16 + (lane & 15)][ko];
            short8 b3 = *(short8*)&B3s[n * 16 + (lane & 15)][ko];
            acc1[0][n] = __builtin_amdgcn_mfma_f32_16x16x32_bf16(a0, b1, acc1[0][n], 0, 0, 0);
            acc1[1][n] = __builtin_amdgcn_mfma_f32_16x16x32_bf16(a1, b1, acc1[1][n], 0, 0, 0);
            acc3[0][n] = __builtin_amdgcn_mfma_f32_16x16x32_bf16(a0, b3, acc3[0][n], 0, 0, 0);
            acc3[1][n] = __builtin_amdgcn_mfma_f32_16x16x32_bf16(a1, b3, acc3[1][n], 0, 0, 0);
        }
        __syncthreads();
    }

    int quad = lane >> 4;
#pragma unroll
    for (int m = 0; m < 2; m++)
#pragma unroll
        for (int n = 0; n < 4; n++)
#pragma unroll
            for (int r = 0; r < 4; r++) {
                float h1 = acc1[m][n][r], h3 = acc3[m][n][r];
                float sv = h1 / (1.0f + __expf(-h1)) * h3;
                Hs[w * 32 + m * 16 + quad * 4 + r][n * 16 + (lane & 15)] = f2bf(sv);
            }
    __syncthreads();
    int srow = tid >> 3;            // 0..31
    int scol = (tid & 7) * 8;
#pragma unroll
    for (int it = 0; it < 4; it++) {
        int rr = srow + it * 32;
        if (rr < mval)
            *(int4*)(h + (size_t)(row0 + rr) * H_PAD + nt * BN + scol) = *(int4*)&Hs[rr][scol];
    }
}

// Pass 2: y = h . w2_e^T; out[token] += gate * y (atomic).
__global__ __launch_bounds__(256, 2) void expert_ffn2(
    const unsigned short* __restrict__ h, const unsigned short* __restrict__ w2b,
    const int* __restrict__ offsets, const int* __restrict__ row_token,
    const float* __restrict__ row_gate, float* __restrict__ out) {
    int e = blockIdx.x >> 7;
    int mt = blockIdx.x & 127;
    int nt = blockIdx.y;  // 0..3
    int off0 = offsets[e], off1 = offsets[e + 1];
    int row0 = off0 + mt * BM;
    if (row0 >= off1) return;
    int mval = min(BM, off1 - row0);

    __shared__ unsigned short As[BM][BK];
    __shared__ unsigned short Bs[BN][BK];

    int tid = threadIdx.x, lane = tid & 63, w = tid >> 6;
    int arow = tid >> 2;
    int acol = (tid & 3) * 8;
    int r0 = min(row0 + arow, NROWS - 1);
    int r1 = min(row0 + arow + 64, NROWS - 1);
    const unsigned short* a0p = h + (size_t)r0 * H_PAD + acol;
    const unsigned short* a1p = h + (size_t)r1 * H_PAD + acol;
    int cg = nt * BN + arow;  // < 256
    const unsigned short* bp = w2b + ((size_t)e * C_DIM + cg) * H_PAD + acol;

    floatx4 acc[2][4];
#pragma unroll
    for (int m = 0; m < 2; m++)
#pragma unroll
        for (int n = 0; n < 4; n++) acc[m][n] = (floatx4){0.f, 0.f, 0.f, 0.f};

    int mrow = w * 32 + (lane & 15);
    int ko = (lane >> 4) * 8;
    for (int kt = 0; kt < H_PAD / BK; kt++) {  // 22 steps
        int kb = kt * BK;
        *(int4*)&As[arow][acol] = *(const int4*)(a0p + kb);
        *(int4*)&As[arow + 64][acol] = *(const int4*)(a1p + kb);
        *(int4*)&Bs[arow][acol] = *(const int4*)(bp + kb);
        __syncthreads();
        short8 a0 = *(short8*)&As[mrow][ko];
        short8 a1 = *(short8*)&As[mrow + 16][ko];
#pragma unroll
        for (int n = 0; n < 4; n++) {
            short8 b = *(short8*)&Bs[n * 16 + (lane & 15)][ko];
            acc[0][n] = __builtin_amdgcn_mfma_f32_16x16x32_bf16(a0, b, acc[0][n], 0, 0, 0);
            acc[1][n] = __builtin_amdgcn_mfma_f32_16x16x32_bf16(a1, b, acc[1][n], 0, 0, 0);
        }
        __syncthreads();
    }

    int quad = lane >> 4;
#pragma unroll
    for (int m = 0; m < 2; m++) {
#pragma unroll
        for (int r = 0; r < 4; r++) {
            int rl = w * 32 + m * 16 + quad * 4 + r;
            if (rl < mval) {
                int row = row0 + rl;
                int token = row_token[row];
                float g = row_gate[row];
                float* op = out + (size_t)token * C_DIM + nt * BN + (lane & 15);
#pragma unroll
                for (int n = 0; n < 4; n++) atomicAdd(op + n * 16, g * acc[m][n][r]);
            }
        }
    }
}

extern "C" void kernel_launch(void* const* d_in, const int* in_sizes, int n_in,
                              void* d_out, int out_size, void* d_ws, size_t ws_size,
                              hipStream_t stream) {
    const float* x = (const float*)d_in[0];
    const float* rw = (const float*)d_in[1];
    const float* w1 = (const float*)d_in[2];
    const float* w2 = (const float*)d_in[3];
    const float* w3 = (const float*)d_in[4];
    float* out = (float*)d_out;

    char* ws = (char*)d_ws;
    size_t o = 0;
    auto alloc = [&](size_t bytes) {
        void* p = ws + o;
        o = (o + bytes + 255) & ~(size_t)255;
        return p;
    };
    unsigned short* xb = (unsigned short*)alloc((size_t)N_TOK * C_DIM * 2);
    unsigned short* w1b = (unsigned short*)alloc((size_t)E_NUM * H_PAD * C_DIM * 2);
    unsigned short* w3b = (unsigned short*)alloc((size_t)E_NUM * H_PAD * C_DIM * 2);
    unsigned short* w2b = (unsigned short*)alloc((size_t)E_NUM * C_DIM * H_PAD * 2);
    unsigned short* hbuf = (unsigned short*)alloc((size_t)NROWS * H_PAD * 2);
    int* offsets = (int*)alloc((E_NUM + 1) * 4);
    int* as_e = (int*)alloc(NROWS * 4);
    float* as_gate = (float*)alloc(NROWS * 4);
    int* row_token = (int*)alloc(NROWS * 4);
    float* row_gate = (float*)alloc(NROWS * 4);

    hipMemsetAsync(out, 0, (size_t)N_TOK * C_DIM * 4, stream);

    int tx = N_TOK * C_DIM;
    convert_pad<<<(tx + 255) / 256, 256, 0, stream>>>(x, xb, N_TOK, N_TOK, C_DIM, C_DIM, tx);
    int tw13 = E_NUM * H_PAD * C_DIM;
    convert_pad<<<(tw13 + 255) / 256, 256, 0, stream>>>(w1, w1b, H_DIM, H_PAD, C_DIM, C_DIM, tw13);
    convert_pad<<<(tw13 + 255) / 256, 256, 0, stream>>>(w3, w3b, H_DIM, H_PAD, C_DIM, C_DIM, tw13);
    int tw2 = E_NUM * C_DIM * H_PAD;
    convert_pad<<<(tw2 + 255) / 256, 256, 0, stream>>>(w2, w2b, C_DIM, C_DIM, H_DIM, H_PAD, tw2);

    router_kernel<<<N_TOK / 4, 256, 0, stream>>>(x, rw, as_e, as_gate);
    bin_kernel<<<1, 256, 0, stream>>>(as_e, as_gate, offsets, row_token, row_gate);

    expert_ffn1<<<dim3(E_NUM * 128, H_PAD / BN), 256, 0, stream>>>(xb, w1b, w3b, offsets, row_token, hbuf);
    expert_ffn2<<<dim3(E_NUM * 128, C_DIM / BN), 256, 0, stream>>>(hbuf, w2b, offsets, row_token, row_gate, out);
}

// Round 3
// 232.271 us; speedup vs baseline: 2.6051x; 1.3073x over previous
//
#include <hip/hip_runtime.h>
#include <hip/hip_bf16.h>

#define N_TOK 16384
#define C_DIM 256
#define E_NUM 8
#define H_DIM 682
#define H_PAD 704          // 22 * 32
#define NROWS (N_TOK * 2)  // total expert-assignments (top-2)
#define HB 64              // histogram/scatter blocks
#define APB (NROWS / HB)   // assignments per block = 512

typedef short short8 __attribute__((ext_vector_type(8)));
typedef float floatx4 __attribute__((ext_vector_type(4)));

__device__ inline unsigned short f2bf(float v) {
    union { float f; unsigned int u; } x; x.f = v;
    unsigned int r = (x.u + 0x7fffu + ((x.u >> 16) & 1u)) >> 16;
    return (unsigned short)r;
}

// Async global->LDS 16B/lane. LDS dst: wave-uniform base + lane*16.
__device__ __forceinline__ void load_lds16(const void* g, void* l) {
    __builtin_amdgcn_global_load_lds(
        (const __attribute__((address_space(1))) unsigned int*)g,
        (__attribute__((address_space(3))) unsigned int*)l, 16, 0, 0);
}

// Generic fp32 -> bf16 convert with zero padding. dst is [mats][Rd][Cd],
// src is [mats][Rs][Cs]; pad region (r>=Rs || c>=Cs) written as 0.
__global__ void convert_pad(const float* __restrict__ src, unsigned short* __restrict__ dst,
                            int Rs, int Rd, int Cs, int Cd, int total) {
    int idx = blockIdx.x * blockDim.x + threadIdx.x;
    if (idx >= total) return;
    int per = Rd * Cd;
    int e = idx / per;
    int rem = idx - e * per;
    int r = rem / Cd;
    int c = rem - r * Cd;
    float v = (r < Rs && c < Cs) ? src[((size_t)e * Rs + r) * Cs + c] : 0.0f;
    dst[idx] = f2bf(v);
}

// fp32 router: one wave per token. logits -> softmax -> top2 -> renorm gates.
__global__ __launch_bounds__(256) void router_kernel(
    const float* __restrict__ x, const float* __restrict__ rw,
    int* __restrict__ as_e, float* __restrict__ as_gate) {
    __shared__ float rws[E_NUM * C_DIM];
    int tid = threadIdx.x;
    for (int i = tid; i < E_NUM * C_DIM; i += 256) rws[i] = rw[i];
    __syncthreads();
    int wave = tid >> 6, lane = tid & 63;
    int t = blockIdx.x * 4 + wave;
    const float4 xv = *(const float4*)(x + (size_t)t * C_DIM + lane * 4);
    float p[E_NUM];
#pragma unroll
    for (int e = 0; e < E_NUM; e++) {
        const float* wr = &rws[e * C_DIM + lane * 4];
        p[e] = xv.x * wr[0] + xv.y * wr[1] + xv.z * wr[2] + xv.w * wr[3];
    }
#pragma unroll
    for (int off = 32; off >= 1; off >>= 1) {
#pragma unroll
        for (int e = 0; e < E_NUM; e++) p[e] += __shfl_down(p[e], off, 64);
    }
    if (lane == 0) {
        float m = p[0];
#pragma unroll
        for (int e = 1; e < E_NUM; e++) m = fmaxf(m, p[e]);
        float s = 0.f, q[E_NUM];
#pragma unroll
        for (int e = 0; e < E_NUM; e++) { q[e] = expf(p[e] - m); s += q[e]; }
#pragma unroll
        for (int e = 0; e < E_NUM; e++) q[e] /= s;
        int e0 = 0;
#pragma unroll
        for (int e = 1; e < E_NUM; e++) if (q[e] > q[e0]) e0 = e;
        int e1 = (e0 == 0) ? 1 : 0;
#pragma unroll
        for (int e = 0; e < E_NUM; e++) {
            if (e != e0 && q[e] > q[e1]) e1 = e;
        }
        float g0 = q[e0], g1 = q[e1];
        float denom = g0 + g1 + 1e-9f;
        g0 /= denom; g1 /= denom;
        as_e[t * 2] = e0; as_gate[t * 2] = g0;
        as_e[t * 2 + 1] = e1; as_gate[t * 2 + 1] = g1;
    }
}

// Per-block expert histogram (LDS atomics), 64 blocks x 512 assignments.
__global__ __launch_bounds__(256) void hist_kernel(const int* __restrict__ as_e,
                                                   int* __restrict__ block_hist) {
    __shared__ int lh[E_NUM];
    int b = blockIdx.x, tid = threadIdx.x;
    if (tid < E_NUM) lh[tid] = 0;
    __syncthreads();
    for (int i = tid; i < APB; i += 256) atomicAdd(&lh[as_e[b * APB + i]], 1);
    __syncthreads();
    if (tid < E_NUM) block_hist[b * E_NUM + tid] = lh[tid];
}

// Scan: expert totals -> offsets[9]; per-(block,expert) base cursors.
__global__ void scan2_kernel(const int* __restrict__ block_hist, int* __restrict__ offsets,
                             int* __restrict__ block_base) {
    __shared__ int tot[E_NUM], off[E_NUM];
    int e = threadIdx.x;
    if (e < E_NUM) {
        int s = 0;
        for (int b = 0; b < HB; b++) s += block_hist[b * E_NUM + e];
        tot[e] = s;
    }
    __syncthreads();
    if (e == 0) {
        int acc = 0;
        for (int i = 0; i < E_NUM; i++) { off[i] = acc; offsets[i] = acc; acc += tot[i]; }
        offsets[E_NUM] = acc;
    }
    __syncthreads();
    if (e < E_NUM) {
        int acc = off[e];
        for (int b = 0; b < HB; b++) { block_base[b * E_NUM + e] = acc; acc += block_hist[b * E_NUM + e]; }
    }
}

// Scatter: slot = block_base[b][e] + LDS cursor. Order within an expert
// segment is irrelevant (each row carries its own gate; combination is a sum).
__global__ __launch_bounds__(256) void scatter_kernel(
    const int* __restrict__ as_e, const float* __restrict__ as_gate,
    const int* __restrict__ block_base, int* __restrict__ row_token,
    float* __restrict__ row_gate) {
    __shared__ int cur[E_NUM];
    int b = blockIdx.x, tid = threadIdx.x;
    if (tid < E_NUM) cur[tid] = block_base[b * E_NUM + tid];
    __syncthreads();
    for (int i = tid; i < APB; i += 256) {
        int a = b * APB + i;
        int e = as_e[a];
        int p = atomicAdd(&cur[e], 1);
        row_token[p] = a >> 1;
        row_gate[p] = as_gate[a];
    }
}

#define BM 128
#define BN 64
#define BK 32

// Pass 1: h[row][0..H_PAD) = silu(x_row . w1_e^T) * (x_row . w3_e^T), bf16.
// Staging via global_load_lds (16B/lane, lane-contiguous LDS tiles, no pad).
__global__ __launch_bounds__(256, 2) void expert_ffn1(
    const unsigned short* __restrict__ xb, const unsigned short* __restrict__ w1b,
    const unsigned short* __restrict__ w3b, const int* __restrict__ offsets,
    const int* __restrict__ row_token, unsigned short* __restrict__ h) {
    int e = blockIdx.x >> 7;
    int mt = blockIdx.x & 127;
    int nt = blockIdx.y;  // 0..10
    int off0 = offsets[e], off1 = offsets[e + 1];
    int row0 = off0 + mt * BM;
    if (row0 >= off1) return;
    int mval = min(BM, off1 - row0);

    __shared__ unsigned short As[BM][BK];
    __shared__ unsigned short B1s[BN][BK];
    __shared__ unsigned short B3s[BN][BK];
    __shared__ unsigned short Hs[BM][BN + 8];  // +8 shorts: rows stay 16B-aligned

    int tid = threadIdx.x;
    int lane = tid & 63, w = tid >> 6;
    int arow = tid >> 2;            // 0..63
    int acol = (tid & 3) * 8;       // 16B chunks
    // Rows beyond mval gather from token row 0; results discarded by store guard.
    int tok0 = (arow < mval) ? row_token[row0 + arow] : 0;
    int tok1 = (arow + 64 < mval) ? row_token[row0 + arow + 64] : 0;
    const unsigned short* a0p = xb + (size_t)tok0 * C_DIM + acol;
    const unsigned short* a1p = xb + (size_t)tok1 * C_DIM + acol;
    int ng = nt * BN + arow;  // < 704 always
    const unsigned short* b1p = w1b + ((size_t)e * H_PAD + ng) * C_DIM + acol;
    const unsigned short* b3p = w3b + ((size_t)e * H_PAD + ng) * C_DIM + acol;

    // Wave-uniform LDS staging bases (lane-contiguous: flat offset = tid*16B).
    unsigned short* As0_b = &As[w * 16][0];
    unsigned short* As1_b = &As[64 + w * 16][0];
    unsigned short* B1_b = &B1s[w * 16][0];
    unsigned short* B3_b = &B3s[w * 16][0];

    floatx4 acc1[2][4], acc3[2][4];
#pragma unroll
    for (int m = 0; m < 2; m++)
#pragma unroll
        for (int n = 0; n < 4; n++) {
            acc1[m][n] = (floatx4){0.f, 0.f, 0.f, 0.f};
            acc3[m][n] = (floatx4){0.f, 0.f, 0.f, 0.f};
        }

    int mrow = w * 32 + (lane & 15);
    int ko = (lane >> 4) * 8;
    for (int kt = 0; kt < C_DIM / BK; kt++) {
        int kb = kt * BK;
        load_lds16(a0p + kb, As0_b);
        load_lds16(a1p + kb, As1_b);
        load_lds16(b1p + kb, B1_b);
        load_lds16(b3p + kb, B3_b);
        __syncthreads();
        short8 a0 = *(short8*)&As[mrow][ko];
        short8 a1 = *(short8*)&As[mrow + 16][ko];
#pragma unroll
        for (int n = 0; n < 4; n++) {
            short8 b1 = *(short8*)&B1s[n * 16 + (lane & 15)][ko];
            short8 b3 = *(short8*)&B3s[n * 16 + (lane & 15)][ko];
            acc1[0][n] = __builtin_amdgcn_mfma_f32_16x16x32_bf16(a0, b1, acc1[0][n], 0, 0, 0);
            acc1[1][n] = __builtin_amdgcn_mfma_f32_16x16x32_bf16(a1, b1, acc1[1][n], 0, 0, 0);
            acc3[0][n] = __builtin_amdgcn_mfma_f32_16x16x32_bf16(a0, b3, acc3[0][n], 0, 0, 0);
            acc3[1][n] = __builtin_amdgcn_mfma_f32_16x16x32_bf16(a1, b3, acc3[1][n], 0, 0, 0);
        }
        __syncthreads();
    }

    int quad = lane >> 4;
#pragma unroll
    for (int m = 0; m < 2; m++)
#pragma unroll
        for (int n = 0; n < 4; n++)
#pragma unroll
            for (int r = 0; r < 4; r++) {
                float h1 = acc1[m][n][r], h3 = acc3[m][n][r];
                float sv = h1 / (1.0f + __expf(-h1)) * h3;
                Hs[w * 32 + m * 16 + quad * 4 + r][n * 16 + (lane & 15)] = f2bf(sv);
            }
    __syncthreads();
    int srow = tid >> 3;            // 0..31
    int scol = (tid & 7) * 8;
#pragma unroll
    for (int it = 0; it < 4; it++) {
        int rr = srow + it * 32;
        if (rr < mval)
            *(int4*)(h + (size_t)(row0 + rr) * H_PAD + nt * BN + scol) = *(int4*)&Hs[rr][scol];
    }
}

// Pass 2: y = h . w2_e^T; out[token] += gate * y (atomic).
__global__ __launch_bounds__(256, 2) void expert_ffn2(
    const unsigned short* __restrict__ h, const unsigned short* __restrict__ w2b,
    const int* __restrict__ offsets, const int* __restrict__ row_token,
    const float* __restrict__ row_gate, float* __restrict__ out) {
    int e = blockIdx.x >> 7;
    int mt = blockIdx.x & 127;
    int nt = blockIdx.y;  // 0..3
    int off0 = offsets[e], off1 = offsets[e + 1];
    int row0 = off0 + mt * BM;
    if (row0 >= off1) return;
    int mval = min(BM, off1 - row0);

    __shared__ unsigned short As[BM][BK];
    __shared__ unsigned short Bs[BN][BK];

    int tid = threadIdx.x, lane = tid & 63, w = tid >> 6;
    int arow = tid >> 2;
    int acol = (tid & 3) * 8;
    int r0 = min(row0 + arow, NROWS - 1);
    int r1 = min(row0 + arow + 64, NROWS - 1);
    const unsigned short* a0p = h + (size_t)r0 * H_PAD + acol;
    const unsigned short* a1p = h + (size_t)r1 * H_PAD + acol;
    int cg = nt * BN + arow;  // < 256
    const unsigned short* bp = w2b + ((size_t)e * C_DIM + cg) * H_PAD + acol;

    unsigned short* As0_b = &As[w * 16][0];
    unsigned short* As1_b = &As[64 + w * 16][0];
    unsigned short* Bs_b = &Bs[w * 16][0];

    floatx4 acc[2][4];
#pragma unroll
    for (int m = 0; m < 2; m++)
#pragma unroll
        for (int n = 0; n < 4; n++) acc[m][n] = (floatx4){0.f, 0.f, 0.f, 0.f};

    int mrow = w * 32 + (lane & 15);
    int ko = (lane >> 4) * 8;
    for (int kt = 0; kt < H_PAD / BK; kt++) {  // 22 steps
        int kb = kt * BK;
        load_lds16(a0p + kb, As0_b);
        load_lds16(a1p + kb, As1_b);
        load_lds16(bp + kb, Bs_b);
        __syncthreads();
        short8 a0 = *(short8*)&As[mrow][ko];
        short8 a1 = *(short8*)&As[mrow + 16][ko];
#pragma unroll
        for (int n = 0; n < 4; n++) {
            short8 b = *(short8*)&Bs[n * 16 + (lane & 15)][ko];
            acc[0][n] = __builtin_amdgcn_mfma_f32_16x16x32_bf16(a0, b, acc[0][n], 0, 0, 0);
            acc[1][n] = __builtin_amdgcn_mfma_f32_16x16x32_bf16(a1, b, acc[1][n], 0, 0, 0);
        }
        __syncthreads();
    }

    int quad = lane >> 4;
#pragma unroll
    for (int m = 0; m < 2; m++) {
#pragma unroll
        for (int r = 0; r < 4; r++) {
            int rl = w * 32 + m * 16 + quad * 4 + r;
            if (rl < mval) {
                int row = row0 + rl;
                int token = row_token[row];
                float g = row_gate[row];
                float* op = out + (size_t)token * C_DIM + nt * BN + (lane & 15);
#pragma unroll
                for (int n = 0; n < 4; n++) atomicAdd(op + n * 16, g * acc[m][n][r]);
            }
        }
    }
}

extern "C" void kernel_launch(void* const* d_in, const int* in_sizes, int n_in,
                              void* d_out, int out_size, void* d_ws, size_t ws_size,
                              hipStream_t stream) {
    const float* x = (const float*)d_in[0];
    const float* rw = (const float*)d_in[1];
    const float* w1 = (const float*)d_in[2];
    const float* w2 = (const float*)d_in[3];
    const float* w3 = (const float*)d_in[4];
    float* out = (float*)d_out;

    char* ws = (char*)d_ws;
    size_t o = 0;
    auto alloc = [&](size_t bytes) {
        void* p = ws + o;
        o = (o + bytes + 255) & ~(size_t)255;
        return p;
    };
    unsigned short* xb = (unsigned short*)alloc((size_t)N_TOK * C_DIM * 2);
    unsigned short* w1b = (unsigned short*)alloc((size_t)E_NUM * H_PAD * C_DIM * 2);
    unsigned short* w3b = (unsigned short*)alloc((size_t)E_NUM * H_PAD * C_DIM * 2);
    unsigned short* w2b = (unsigned short*)alloc((size_t)E_NUM * C_DIM * H_PAD * 2);
    unsigned short* hbuf = (unsigned short*)alloc((size_t)NROWS * H_PAD * 2);
    int* offsets = (int*)alloc((E_NUM + 1) * 4);
    int* as_e = (int*)alloc(NROWS * 4);
    float* as_gate = (float*)alloc(NROWS * 4);
    int* row_token = (int*)alloc(NROWS * 4);
    float* row_gate = (float*)alloc(NROWS * 4);
    int* block_hist = (int*)alloc(HB * E_NUM * 4);
    int* block_base = (int*)alloc(HB * E_NUM * 4);

    hipMemsetAsync(out, 0, (size_t)N_TOK * C_DIM * 4, stream);

    int tx = N_TOK * C_DIM;
    convert_pad<<<(tx + 255) / 256, 256, 0, stream>>>(x, xb, N_TOK, N_TOK, C_DIM, C_DIM, tx);
    int tw13 = E_NUM * H_PAD * C_DIM;
    convert_pad<<<(tw13 + 255) / 256, 256, 0, stream>>>(w1, w1b, H_DIM, H_PAD, C_DIM, C_DIM, tw13);
    convert_pad<<<(tw13 + 255) / 256, 256, 0, stream>>>(w3, w3b, H_DIM, H_PAD, C_DIM, C_DIM, tw13);
    int tw2 = E_NUM * C_DIM * H_PAD;
    convert_pad<<<(tw2 + 255) / 256, 256, 0, stream>>>(w2, w2b, C_DIM, C_DIM, H_DIM, H_PAD, tw2);

    router_kernel<<<N_TOK / 4, 256, 0, stream>>>(x, rw, as_e, as_gate);
    hist_kernel<<<HB, 256, 0, stream>>>(as_e, block_hist);
    scan2_kernel<<<1, 64, 0, stream>>>(block_hist, offsets, block_base);
    scatter_kernel<<<HB, 256, 0, stream>>>(as_e, as_gate, block_base, row_token, row_gate);

    expert_ffn1<<<dim3(E_NUM * 128, H_PAD / BN), 256, 0, stream>>>(xb, w1b, w3b, offsets, row_token, hbuf);
    expert_ffn2<<<dim3(E_NUM * 128, C_DIM / BN), 256, 0, stream>>>(hbuf, w2b, offsets, row_token, row_gate, out);
}

// Round 4
// 214.455 us; speedup vs baseline: 2.8215x; 1.0831x over previous
//
#include <hip/hip_runtime.h>
#include <hip/hip_bf16.h>

#define N_TOK 16384
#define C_DIM 256
#define E_NUM 8
#define H_DIM 682
#define H_PAD 768          // 6 * 128 (pad rows/cols are exact zeros)
#define NROWS (N_TOK * 2)  // total expert-assignments (top-2)
#define HB 64              // histogram/scatter blocks
#define APB (NROWS / HB)   // assignments per block = 512

typedef short short8 __attribute__((ext_vector_type(8)));
typedef float floatx4 __attribute__((ext_vector_type(4)));
typedef unsigned int uint;

__device__ inline unsigned short f2bf(float v) {
    union { float f; uint u; } x; x.f = v;
    uint r = (x.u + 0x7fffu + ((x.u >> 16) & 1u)) >> 16;
    return (unsigned short)r;
}
__device__ inline float bf2f(unsigned short v) {
    union { uint u; float f; } x; x.u = ((uint)v) << 16; return x.f;
}

// Async global->LDS 16B/lane. LDS dst: wave-uniform base + lane*16.
__device__ __forceinline__ void load_lds16(const void* g, void* l) {
    __builtin_amdgcn_global_load_lds(
        (const __attribute__((address_space(1))) unsigned int*)g,
        (__attribute__((address_space(3))) unsigned int*)l, 16, 0, 0);
}

// Fused weight convert: w1,w3 [E][682][256] -> [E][768][256] bf16 (zero pad rows);
// w2 [E][256][682] -> [E][256][768] bf16 (zero pad cols). Pair-granular (uint writes).
#define P13 (E_NUM * H_PAD * (C_DIM / 2))
#define P2  (E_NUM * C_DIM * (H_PAD / 2))
__global__ void wconvert(const float* __restrict__ w1, const float* __restrict__ w3,
                         const float* __restrict__ w2, unsigned short* __restrict__ w1b,
                         unsigned short* __restrict__ w3b, unsigned short* __restrict__ w2b) {
    int idx = blockIdx.x * 256 + threadIdx.x;
    if (idx < 2 * P13) {
        const float* src = (idx < P13) ? w1 : w3;
        unsigned short* dst = (idx < P13) ? w1b : w3b;
        int i = (idx < P13) ? idx : idx - P13;
        int e = i / (H_PAD * (C_DIM / 2));
        int rem = i - e * (H_PAD * (C_DIM / 2));
        int r = rem / (C_DIM / 2);
        int c2 = rem - r * (C_DIM / 2);
        uint v = 0;
        if (r < H_DIM) {
            const float2 f = *(const float2*)(src + ((size_t)e * H_DIM + r) * C_DIM + c2 * 2);
            v = (uint)f2bf(f.x) | ((uint)f2bf(f.y) << 16);
        }
        ((uint*)dst)[i] = v;
    } else if (idx < 2 * P13 + P2) {
        int i = idx - 2 * P13;
        int e = i / (C_DIM * (H_PAD / 2));
        int rem = i - e * (C_DIM * (H_PAD / 2));
        int r = rem / (H_PAD / 2);
        int c2 = rem - r * (H_PAD / 2);
        uint v = 0;
        if (c2 * 2 < H_DIM) {  // H_DIM even -> clean pair boundary
            const float2 f = *(const float2*)(w2 + ((size_t)e * C_DIM + r) * H_DIM + c2 * 2);
            v = (uint)f2bf(f.x) | ((uint)f2bf(f.y) << 16);
        }
        ((uint*)w2b)[i] = v;
    }
}

// fp32 router (one wave/token): logits -> softmax -> top2 -> renorm gates.
// Also emits xb = bf16(x) (fused convert; x is already being read here).
__global__ __launch_bounds__(256) void router_kernel(
    const float* __restrict__ x, const float* __restrict__ rw,
    unsigned short* __restrict__ xb, int* __restrict__ as_e, float* __restrict__ as_gate) {
    __shared__ float rws[E_NUM * C_DIM];
    int tid = threadIdx.x;
    for (int i = tid; i < E_NUM * C_DIM; i += 256) rws[i] = rw[i];
    __syncthreads();
    int wave = tid >> 6, lane = tid & 63;
    int t = blockIdx.x * 4 + wave;
    const float4 xv = *(const float4*)(x + (size_t)t * C_DIM + lane * 4);
    uint2 pk;
    pk.x = (uint)f2bf(xv.x) | ((uint)f2bf(xv.y) << 16);
    pk.y = (uint)f2bf(xv.z) | ((uint)f2bf(xv.w) << 16);
    *(uint2*)(xb + (size_t)t * C_DIM + lane * 4) = pk;
    float p[E_NUM];
#pragma unroll
    for (int e = 0; e < E_NUM; e++) {
        const float* wr = &rws[e * C_DIM + lane * 4];
        p[e] = xv.x * wr[0] + xv.y * wr[1] + xv.z * wr[2] + xv.w * wr[3];
    }
#pragma unroll
    for (int off = 32; off >= 1; off >>= 1) {
#pragma unroll
        for (int e = 0; e < E_NUM; e++) p[e] += __shfl_down(p[e], off, 64);
    }
    if (lane == 0) {
        float m = p[0];
#pragma unroll
        for (int e = 1; e < E_NUM; e++) m = fmaxf(m, p[e]);
        float s = 0.f, q[E_NUM];
#pragma unroll
        for (int e = 0; e < E_NUM; e++) { q[e] = expf(p[e] - m); s += q[e]; }
#pragma unroll
        for (int e = 0; e < E_NUM; e++) q[e] /= s;
        int e0 = 0;
#pragma unroll
        for (int e = 1; e < E_NUM; e++) if (q[e] > q[e0]) e0 = e;
        int e1 = (e0 == 0) ? 1 : 0;
#pragma unroll
        for (int e = 0; e < E_NUM; e++) {
            if (e != e0 && q[e] > q[e1]) e1 = e;
        }
        float g0 = q[e0], g1 = q[e1];
        float denom = g0 + g1 + 1e-9f;
        g0 /= denom; g1 /= denom;
        as_e[t * 2] = e0; as_gate[t * 2] = g0;
        as_e[t * 2 + 1] = e1; as_gate[t * 2 + 1] = g1;
    }
}

// Per-block expert histogram (LDS atomics), 64 blocks x 512 assignments.
__global__ __launch_bounds__(256) void hist_kernel(const int* __restrict__ as_e,
                                                   int* __restrict__ block_hist) {
    __shared__ int lh[E_NUM];
    int b = blockIdx.x, tid = threadIdx.x;
    if (tid < E_NUM) lh[tid] = 0;
    __syncthreads();
    for (int i = tid; i < APB; i += 256) atomicAdd(&lh[as_e[b * APB + i]], 1);
    __syncthreads();
    if (tid < E_NUM) block_hist[b * E_NUM + tid] = lh[tid];
}

// Scan: expert totals -> offsets[9]; per-(block,expert) base cursors.
__global__ void scan2_kernel(const int* __restrict__ block_hist, int* __restrict__ offsets,
                             int* __restrict__ block_base) {
    __shared__ int tot[E_NUM], off[E_NUM];
    int e = threadIdx.x;
    if (e < E_NUM) {
        int s = 0;
        for (int b = 0; b < HB; b++) s += block_hist[b * E_NUM + e];
        tot[e] = s;
    }
    __syncthreads();
    if (e == 0) {
        int acc = 0;
        for (int i = 0; i < E_NUM; i++) { off[i] = acc; offsets[i] = acc; acc += tot[i]; }
        offsets[E_NUM] = acc;
    }
    __syncthreads();
    if (e < E_NUM) {
        int acc = off[e];
        for (int b = 0; b < HB; b++) { block_base[b * E_NUM + e] = acc; acc += block_hist[b * E_NUM + e]; }
    }
}

// Scatter: row_token (expert-sorted) + inverse map as_row[a] = row.
__global__ __launch_bounds__(256) void scatter_kernel(
    const int* __restrict__ as_e, const int* __restrict__ block_base,
    int* __restrict__ row_token, int* __restrict__ as_row) {
    __shared__ int cur[E_NUM];
    int b = blockIdx.x, tid = threadIdx.x;
    if (tid < E_NUM) cur[tid] = block_base[b * E_NUM + tid];
    __syncthreads();
    for (int i = tid; i < APB; i += 256) {
        int a = b * APB + i;
        int e = as_e[a];
        int p = atomicAdd(&cur[e], 1);
        row_token[p] = a >> 1;
        as_row[a] = p;
    }
}

// ---------------- Pass 1: h = silu(x.w1^T) * (x.w3^T) ----------------
// Block: 128 rows x 128-col chunk; 2x2 waves, each 64x64 per matrix.
// grid.x = E*128 m-tile capacity (early exit), grid.y = 2 (3 chunks each).
__global__ __launch_bounds__(256, 2) void expert_ffn1(
    const unsigned short* __restrict__ xb, const unsigned short* __restrict__ w1b,
    const unsigned short* __restrict__ w3b, const int* __restrict__ offsets,
    const int* __restrict__ row_token, unsigned short* __restrict__ h) {
    int e = blockIdx.x >> 7;
    int mt = blockIdx.x & 127;
    int off0 = offsets[e], off1 = offsets[e + 1];
    int row0 = off0 + mt * 128;
    if (row0 >= off1) return;
    int mval = min(128, off1 - row0);

    __shared__ union {
        struct { unsigned short A[128 * 32], B1[128 * 32], B3[128 * 32]; } s;
        unsigned short Hs[128 * 136];  // 136-short rows: 272 B = 17*16 (aligned)
    } sm;

    int tid = threadIdx.x, lane = tid & 63, w = tid >> 6;
    int wm = w & 1, wn = w >> 1;
    int ra = tid >> 2;             // staging row (round 0); +64 for round 1
    int acol = (tid & 3) * 8;      // 16B chunk within 32-col k-tile
    int tok0 = row_token[row0 + min(ra, mval - 1)];
    int tok1 = row_token[row0 + min(ra + 64, mval - 1)];
    const unsigned short* a0p = xb + (size_t)tok0 * C_DIM + acol;
    const unsigned short* a1p = xb + (size_t)tok1 * C_DIM + acol;

    unsigned short* ldsA0 = sm.s.A + w * 512;
    unsigned short* ldsA1 = sm.s.A + 2048 + w * 512;
    unsigned short* ldsB10 = sm.s.B1 + w * 512;
    unsigned short* ldsB11 = sm.s.B1 + 2048 + w * 512;
    unsigned short* ldsB30 = sm.s.B3 + w * 512;
    unsigned short* ldsB31 = sm.s.B3 + 2048 + w * 512;

    int ko = (lane >> 4) * 8;
    int l15 = lane & 15;
    int arowf = wm * 64 + l15;
    int browf = wn * 64 + l15;
    int quad = lane >> 4;

    for (int ci = 0; ci < 3; ci++) {
        int c = blockIdx.y * 3 + ci;
        const unsigned short* b1p0 = w1b + ((size_t)e * H_PAD + c * 128 + ra) * C_DIM + acol;
        const unsigned short* b1p1 = b1p0 + (size_t)64 * C_DIM;
        const unsigned short* b3p0 = w3b + ((size_t)e * H_PAD + c * 128 + ra) * C_DIM + acol;
        const unsigned short* b3p1 = b3p0 + (size_t)64 * C_DIM;

        floatx4 acc1[4][4], acc3[4][4];
#pragma unroll
        for (int m = 0; m < 4; m++)
#pragma unroll
            for (int n = 0; n < 4; n++) {
                acc1[m][n] = (floatx4){0.f, 0.f, 0.f, 0.f};
                acc3[m][n] = (floatx4){0.f, 0.f, 0.f, 0.f};
            }

        for (int kt = 0; kt < 8; kt++) {
            int kb = kt * 32;
            load_lds16(a0p + kb, ldsA0);
            load_lds16(a1p + kb, ldsA1);
            load_lds16(b1p0 + kb, ldsB10);
            load_lds16(b1p1 + kb, ldsB11);
            load_lds16(b3p0 + kb, ldsB30);
            load_lds16(b3p1 + kb, ldsB31);
            __syncthreads();
            short8 af[4], b1f[4], b3f[4];
#pragma unroll
            for (int m = 0; m < 4; m++) af[m] = *(short8*)&sm.s.A[(arowf + m * 16) * 32 + ko];
#pragma unroll
            for (int n = 0; n < 4; n++) {
                b1f[n] = *(short8*)&sm.s.B1[(browf + n * 16) * 32 + ko];
                b3f[n] = *(short8*)&sm.s.B3[(browf + n * 16) * 32 + ko];
            }
#pragma unroll
            for (int m = 0; m < 4; m++)
#pragma unroll
                for (int n = 0; n < 4; n++) {
                    acc1[m][n] = __builtin_amdgcn_mfma_f32_16x16x32_bf16(af[m], b1f[n], acc1[m][n], 0, 0, 0);
                    acc3[m][n] = __builtin_amdgcn_mfma_f32_16x16x32_bf16(af[m], b3f[n], acc3[m][n], 0, 0, 0);
                }
            __syncthreads();
        }

        // Epilogue: silu(h1)*h3 -> Hs (bf16) -> coalesced 16B stores
#pragma unroll
        for (int m = 0; m < 4; m++)
#pragma unroll
            for (int n = 0; n < 4; n++)
#pragma unroll
                for (int r = 0; r < 4; r++) {
                    float h1 = acc1[m][n][r], h3 = acc3[m][n][r];
                    float sv = h1 / (1.0f + __expf(-h1)) * h3;
                    sm.Hs[(wm * 64 + m * 16 + quad * 4 + r) * 136 + wn * 64 + n * 16 + l15] = f2bf(sv);
                }
        __syncthreads();
#pragma unroll
        for (int it = 0; it < 8; it++) {
            int s = it * 256 + tid;
            int row = s >> 4, c16 = s & 15;
            if (row < mval)
                *(int4*)(h + (size_t)(row0 + row) * H_PAD + c * 128 + c16 * 8) =
                    *(int4*)&sm.Hs[row * 136 + c16 * 8];
        }
        __syncthreads();  // Hs dead before next chunk's staging
    }
}

// ---------------- Pass 2: y = h . w2^T (bf16 y, no atomics) ----------------
// Block: 128 rows x full C=256; 2x2 waves, each 64x128. K = 768.
__global__ __launch_bounds__(256, 2) void expert_ffn2(
    const unsigned short* __restrict__ h, const unsigned short* __restrict__ w2b,
    const int* __restrict__ offsets, unsigned short* __restrict__ y) {
    int e = blockIdx.x >> 7;
    int mt = blockIdx.x & 127;
    int off0 = offsets[e], off1 = offsets[e + 1];
    int row0 = off0 + mt * 128;
    if (row0 >= off1) return;
    int mval = min(128, off1 - row0);

    __shared__ union {
        struct { unsigned short A[128 * 32], B[256 * 32]; } s;
        unsigned short Hs[128 * 136];
    } sm;

    int tid = threadIdx.x, lane = tid & 63, w = tid >> 6;
    int wm = w & 1, wn = w >> 1;
    int ra = tid >> 2;
    int acol = (tid & 3) * 8;
    const unsigned short* ap0 = h + (size_t)(row0 + ra) * H_PAD + acol;
    const unsigned short* ap1 = ap0 + (size_t)64 * H_PAD;
    const unsigned short* bp = w2b + ((size_t)e * C_DIM + ra) * H_PAD + acol;

    unsigned short* ldsA0 = sm.s.A + w * 512;
    unsigned short* ldsA1 = sm.s.A + 2048 + w * 512;

    floatx4 acc[4][8];
#pragma unroll
    for (int m = 0; m < 4; m++)
#pragma unroll
        for (int n = 0; n < 8; n++) acc[m][n] = (floatx4){0.f, 0.f, 0.f, 0.f};

    int ko = (lane >> 4) * 8;
    int l15 = lane & 15;
    int arowf = wm * 64 + l15;
    int browf = wn * 128 + l15;
    int quad = lane >> 4;

    for (int kt = 0; kt < H_PAD / 32; kt++) {  // 24
        int kb = kt * 32;
        load_lds16(ap0 + kb, ldsA0);
        load_lds16(ap1 + kb, ldsA1);
#pragma unroll
        for (int r = 0; r < 4; r++)
            load_lds16(bp + (size_t)r * 64 * H_PAD + kb, sm.s.B + r * 2048 + w * 512);
        __syncthreads();
        short8 af[4], bf[8];
#pragma unroll
        for (int m = 0; m < 4; m++) af[m] = *(short8*)&sm.s.A[(arowf + m * 16) * 32 + ko];
#pragma unroll
        for (int n = 0; n < 8; n++) bf[n] = *(short8*)&sm.s.B[(browf + n * 16) * 32 + ko];
#pragma unroll
        for (int m = 0; m < 4; m++)
#pragma unroll
            for (int n = 0; n < 8; n++)
                acc[m][n] = __builtin_amdgcn_mfma_f32_16x16x32_bf16(af[m], bf[n], acc[m][n], 0, 0, 0);
        __syncthreads();
    }

    // Epilogue: raw y (bf16) via Hs transpose, two 128-col passes
#pragma unroll
    for (int p = 0; p < 2; p++) {
        if (wn == p) {
#pragma unroll
            for (int m = 0; m < 4; m++)
#pragma unroll
                for (int n = 0; n < 8; n++)
#pragma unroll
                    for (int r = 0; r < 4; r++)
                        sm.Hs[(wm * 64 + m * 16 + quad * 4 + r) * 136 + n * 16 + l15] =
                            f2bf(acc[m][n][r]);
        }
        __syncthreads();
#pragma unroll
        for (int it = 0; it < 8; it++) {
            int s = it * 256 + tid;
            int row = s >> 4, c16 = s & 15;
            if (row < mval)
                *(int4*)(y + (size_t)(row0 + row) * C_DIM + p * 128 + c16 * 8) =
                    *(int4*)&sm.Hs[row * 136 + c16 * 8];
        }
        __syncthreads();
    }
}

// Combine: out[t][:] = g0*y[row(2t)][:] + g1*y[row(2t+1)][:]  (fp32 out)
__global__ __launch_bounds__(256) void combine_kernel(
    const unsigned short* __restrict__ y, const int* __restrict__ as_row,
    const float* __restrict__ as_gate, float* __restrict__ out) {
    int tid = threadIdx.x, lane = tid & 63;
    int t = blockIdx.x * 4 + (tid >> 6);
    int r0 = as_row[2 * t], r1 = as_row[2 * t + 1];
    float g0 = as_gate[2 * t], g1 = as_gate[2 * t + 1];
    uint2 a = *(const uint2*)(y + (size_t)r0 * C_DIM + lane * 4);
    uint2 b = *(const uint2*)(y + (size_t)r1 * C_DIM + lane * 4);
    float4 o;
    o.x = g0 * bf2f((unsigned short)(a.x & 0xffff)) + g1 * bf2f((unsigned short)(b.x & 0xffff));
    o.y = g0 * bf2f((unsigned short)(a.x >> 16)) + g1 * bf2f((unsigned short)(b.x >> 16));
    o.z = g0 * bf2f((unsigned short)(a.y & 0xffff)) + g1 * bf2f((unsigned short)(b.y & 0xffff));
    o.w = g0 * bf2f((unsigned short)(a.y >> 16)) + g1 * bf2f((unsigned short)(b.y >> 16));
    *(float4*)(out + (size_t)t * C_DIM + lane * 4) = o;
}

extern "C" void kernel_launch(void* const* d_in, const int* in_sizes, int n_in,
                              void* d_out, int out_size, void* d_ws, size_t ws_size,
                              hipStream_t stream) {
    const float* x = (const float*)d_in[0];
    const float* rw = (const float*)d_in[1];
    const float* w1 = (const float*)d_in[2];
    const float* w2 = (const float*)d_in[3];
    const float* w3 = (const float*)d_in[4];
    float* out = (float*)d_out;

    char* ws = (char*)d_ws;
    size_t o = 0;
    auto alloc = [&](size_t bytes) {
        void* p = ws + o;
        o = (o + bytes + 255) & ~(size_t)255;
        return p;
    };
    unsigned short* xb = (unsigned short*)alloc((size_t)N_TOK * C_DIM * 2);
    unsigned short* w1b = (unsigned short*)alloc((size_t)E_NUM * H_PAD * C_DIM * 2);
    unsigned short* w3b = (unsigned short*)alloc((size_t)E_NUM * H_PAD * C_DIM * 2);
    unsigned short* w2b = (unsigned short*)alloc((size_t)E_NUM * C_DIM * H_PAD * 2);
    unsigned short* hbuf = (unsigned short*)alloc((size_t)(NROWS + 128) * H_PAD * 2);
    unsigned short* ybuf = (unsigned short*)alloc((size_t)NROWS * C_DIM * 2);
    int* offsets = (int*)alloc((E_NUM + 1) * 4);
    int* as_e = (int*)alloc(NROWS * 4);
    float* as_gate = (float*)alloc(NROWS * 4);
    int* row_token = (int*)alloc(NROWS * 4);
    int* as_row = (int*)alloc(NROWS * 4);
    int* block_hist = (int*)alloc(HB * E_NUM * 4);
    int* block_base = (int*)alloc(HB * E_NUM * 4);

    wconvert<<<(2 * P13 + P2 + 255) / 256, 256, 0, stream>>>(w1, w3, w2, w1b, w3b, w2b);
    router_kernel<<<N_TOK / 4, 256, 0, stream>>>(x, rw, xb, as_e, as_gate);
    hist_kernel<<<HB, 256, 0, stream>>>(as_e, block_hist);
    scan2_kernel<<<1, 64, 0, stream>>>(block_hist, offsets, block_base);
    scatter_kernel<<<HB, 256, 0, stream>>>(as_e, block_base, row_token, as_row);

    expert_ffn1<<<dim3(E_NUM * 128, 2), 256, 0, stream>>>(xb, w1b, w3b, offsets, row_token, hbuf);
    expert_ffn2<<<E_NUM * 128, 256, 0, stream>>>(hbuf, w2b, offsets, ybuf);
    combine_kernel<<<N_TOK / 4, 256, 0, stream>>>(ybuf, as_row, as_gate, out);
}

// Round 6
// 207.556 us; speedup vs baseline: 2.9153x; 1.0332x over previous
//
#include <hip/hip_runtime.h>
#include <hip/hip_bf16.h>

#define N_TOK 16384
#define C_DIM 256
#define E_NUM 8
#define H_DIM 682
#define H_PAD 768          // 6 * 128 (pad rows/cols are exact zeros)
#define NROWS (N_TOK * 2)  // total expert-assignments (top-2)
#define HB 64              // histogram/scatter blocks
#define APB (NROWS / HB)   // assignments per block = 512

typedef short short8 __attribute__((ext_vector_type(8)));
typedef float floatx4 __attribute__((ext_vector_type(4)));
typedef unsigned int uint;

__device__ inline unsigned short f2bf(float v) {
    union { float f; uint u; } x; x.f = v;
    uint r = (x.u + 0x7fffu + ((x.u >> 16) & 1u)) >> 16;
    return (unsigned short)r;
}
__device__ inline float bf2f(unsigned short v) {
    union { uint u; float f; } x; x.u = ((uint)v) << 16; return x.f;
}

// Async global->LDS 16B/lane. LDS dst: wave-uniform base + lane*16.
__device__ __forceinline__ void load_lds16(const void* g, void* l) {
    __builtin_amdgcn_global_load_lds(
        (const __attribute__((address_space(1))) unsigned int*)g,
        (__attribute__((address_space(3))) unsigned int*)l, 16, 0, 0);
}

// Fused weight convert: w1,w3 [E][682][256] -> [E][768][256] bf16 (zero pad rows);
// w2 [E][256][682] -> [E][256][768] bf16 (zero pad cols). Pair-granular (uint writes).
#define P13 (E_NUM * H_PAD * (C_DIM / 2))
#define P2  (E_NUM * C_DIM * (H_PAD / 2))
__global__ void wconvert(const float* __restrict__ w1, const float* __restrict__ w3,
                         const float* __restrict__ w2, unsigned short* __restrict__ w1b,
                         unsigned short* __restrict__ w3b, unsigned short* __restrict__ w2b) {
    int idx = blockIdx.x * 256 + threadIdx.x;
    if (idx < 2 * P13) {
        const float* src = (idx < P13) ? w1 : w3;
        unsigned short* dst = (idx < P13) ? w1b : w3b;
        int i = (idx < P13) ? idx : idx - P13;
        int e = i / (H_PAD * (C_DIM / 2));
        int rem = i - e * (H_PAD * (C_DIM / 2));
        int r = rem / (C_DIM / 2);
        int c2 = rem - r * (C_DIM / 2);
        uint v = 0;
        if (r < H_DIM) {
            const float2 f = *(const float2*)(src + ((size_t)e * H_DIM + r) * C_DIM + c2 * 2);
            v = (uint)f2bf(f.x) | ((uint)f2bf(f.y) << 16);
        }
        ((uint*)dst)[i] = v;
    } else if (idx < 2 * P13 + P2) {
        int i = idx - 2 * P13;
        int e = i / (C_DIM * (H_PAD / 2));
        int rem = i - e * (C_DIM * (H_PAD / 2));
        int r = rem / (H_PAD / 2);
        int c2 = rem - r * (H_PAD / 2);
        uint v = 0;
        if (c2 * 2 < H_DIM) {  // H_DIM even -> clean pair boundary
            const float2 f = *(const float2*)(w2 + ((size_t)e * C_DIM + r) * H_DIM + c2 * 2);
            v = (uint)f2bf(f.x) | ((uint)f2bf(f.y) << 16);
        }
        ((uint*)w2b)[i] = v;
    }
}

// fp32 router (one wave/token): logits -> softmax -> top2 -> renorm gates.
// Also emits xb = bf16(x) (fused convert; x is already being read here).
__global__ __launch_bounds__(256) void router_kernel(
    const float* __restrict__ x, const float* __restrict__ rw,
    unsigned short* __restrict__ xb, int* __restrict__ as_e, float* __restrict__ as_gate) {
    __shared__ float rws[E_NUM * C_DIM];
    int tid = threadIdx.x;
    for (int i = tid; i < E_NUM * C_DIM; i += 256) rws[i] = rw[i];
    __syncthreads();
    int wave = tid >> 6, lane = tid & 63;
    int t = blockIdx.x * 4 + wave;
    const float4 xv = *(const float4*)(x + (size_t)t * C_DIM + lane * 4);
    uint2 pk;
    pk.x = (uint)f2bf(xv.x) | ((uint)f2bf(xv.y) << 16);
    pk.y = (uint)f2bf(xv.z) | ((uint)f2bf(xv.w) << 16);
    *(uint2*)(xb + (size_t)t * C_DIM + lane * 4) = pk;
    float p[E_NUM];
#pragma unroll
    for (int e = 0; e < E_NUM; e++) {
        const float* wr = &rws[e * C_DIM + lane * 4];
        p[e] = xv.x * wr[0] + xv.y * wr[1] + xv.z * wr[2] + xv.w * wr[3];
    }
#pragma unroll
    for (int off = 32; off >= 1; off >>= 1) {
#pragma unroll
        for (int e = 0; e < E_NUM; e++) p[e] += __shfl_down(p[e], off, 64);
    }
    if (lane == 0) {
        float m = p[0];
#pragma unroll
        for (int e = 1; e < E_NUM; e++) m = fmaxf(m, p[e]);
        float s = 0.f, q[E_NUM];
#pragma unroll
        for (int e = 0; e < E_NUM; e++) { q[e] = expf(p[e] - m); s += q[e]; }
#pragma unroll
        for (int e = 0; e < E_NUM; e++) q[e] /= s;
        int e0 = 0;
#pragma unroll
        for (int e = 1; e < E_NUM; e++) if (q[e] > q[e0]) e0 = e;
        int e1 = (e0 == 0) ? 1 : 0;
#pragma unroll
        for (int e = 0; e < E_NUM; e++) {
            if (e != e0 && q[e] > q[e1]) e1 = e;
        }
        float g0 = q[e0], g1 = q[e1];
        float denom = g0 + g1 + 1e-9f;
        g0 /= denom; g1 /= denom;
        as_e[t * 2] = e0; as_gate[t * 2] = g0;
        as_e[t * 2 + 1] = e1; as_gate[t * 2 + 1] = g1;
    }
}

// Per-block expert histogram (LDS atomics), 64 blocks x 512 assignments.
__global__ __launch_bounds__(256) void hist_kernel(const int* __restrict__ as_e,
                                                   int* __restrict__ block_hist) {
    __shared__ int lh[E_NUM];
    int b = blockIdx.x, tid = threadIdx.x;
    if (tid < E_NUM) lh[tid] = 0;
    __syncthreads();
    for (int i = tid; i < APB; i += 256) atomicAdd(&lh[as_e[b * APB + i]], 1);
    __syncthreads();
    if (tid < E_NUM) block_hist[b * E_NUM + tid] = lh[tid];
}

// Scan: expert totals -> offsets[9]; per-(block,expert) base cursors.
__global__ void scan2_kernel(const int* __restrict__ block_hist, int* __restrict__ offsets,
                             int* __restrict__ block_base) {
    __shared__ int tot[E_NUM], off[E_NUM];
    int e = threadIdx.x;
    if (e < E_NUM) {
        int s = 0;
        for (int b = 0; b < HB; b++) s += block_hist[b * E_NUM + e];
        tot[e] = s;
    }
    __syncthreads();
    if (e == 0) {
        int acc = 0;
        for (int i = 0; i < E_NUM; i++) { off[i] = acc; offsets[i] = acc; acc += tot[i]; }
        offsets[E_NUM] = acc;
    }
    __syncthreads();
    if (e < E_NUM) {
        int acc = off[e];
        for (int b = 0; b < HB; b++) { block_base[b * E_NUM + e] = acc; acc += block_hist[b * E_NUM + e]; }
    }
}

// Scatter: row_token (expert-sorted) + inverse map as_row[a] = row.
__global__ __launch_bounds__(256) void scatter_kernel(
    const int* __restrict__ as_e, const int* __restrict__ block_base,
    int* __restrict__ row_token, int* __restrict__ as_row) {
    __shared__ int cur[E_NUM];
    int b = blockIdx.x, tid = threadIdx.x;
    if (tid < E_NUM) cur[tid] = block_base[b * E_NUM + tid];
    __syncthreads();
    for (int i = tid; i < APB; i += 256) {
        int a = b * APB + i;
        int e = as_e[a];
        int p = atomicAdd(&cur[e], 1);
        row_token[p] = a >> 1;
        as_row[a] = p;
    }
}

// ---------------- Pass 1: h = silu(x.w1^T) * (x.w3^T) ----------------
// Block: 128 rows x ONE 128-col chunk (grid.y = 6); 2x2 waves, each 64x64.
// grid.x = E*64 m-tile capacity (early exit on real counts).
__global__ __launch_bounds__(256, 2) void expert_ffn1(
    const unsigned short* __restrict__ xb, const unsigned short* __restrict__ w1b,
    const unsigned short* __restrict__ w3b, const int* __restrict__ offsets,
    const int* __restrict__ row_token, unsigned short* __restrict__ h) {
    int e = blockIdx.x >> 6;
    int mt = blockIdx.x & 63;
    int c = blockIdx.y;  // 0..5
    int off0 = offsets[e], off1 = offsets[e + 1];
    int row0 = off0 + mt * 128;
    if (row0 >= off1) return;
    int mval = min(128, off1 - row0);

    __shared__ union {
        struct { unsigned short A[128 * 32], B1[128 * 32], B3[128 * 32]; } s;
        unsigned short Hs[128 * 136];  // 136-short rows: 272 B = 17*16 (aligned)
    } sm;

    int tid = threadIdx.x, lane = tid & 63, w = tid >> 6;
    int wm = w & 1, wn = w >> 1;
    int ra = tid >> 2;             // staging row (round 0); +64 for round 1
    int acol = (tid & 3) * 8;      // 16B chunk within 32-col k-tile
    int tok0 = row_token[row0 + min(ra, mval - 1)];
    int tok1 = row_token[row0 + min(ra + 64, mval - 1)];
    const unsigned short* a0p = xb + (size_t)tok0 * C_DIM + acol;
    const unsigned short* a1p = xb + (size_t)tok1 * C_DIM + acol;
    const unsigned short* b1p0 = w1b + ((size_t)e * H_PAD + c * 128 + ra) * C_DIM + acol;
    const unsigned short* b1p1 = b1p0 + (size_t)64 * C_DIM;
    const unsigned short* b3p0 = w3b + ((size_t)e * H_PAD + c * 128 + ra) * C_DIM + acol;
    const unsigned short* b3p1 = b3p0 + (size_t)64 * C_DIM;

    unsigned short* ldsA0 = sm.s.A + w * 512;
    unsigned short* ldsA1 = sm.s.A + 2048 + w * 512;
    unsigned short* ldsB10 = sm.s.B1 + w * 512;
    unsigned short* ldsB11 = sm.s.B1 + 2048 + w * 512;
    unsigned short* ldsB30 = sm.s.B3 + w * 512;
    unsigned short* ldsB31 = sm.s.B3 + 2048 + w * 512;

    int ko = (lane >> 4) * 8;
    int l15 = lane & 15;
    int arowf = wm * 64 + l15;
    int browf = wn * 64 + l15;
    int quad = lane >> 4;

    floatx4 acc1[4][4], acc3[4][4];
#pragma unroll
    for (int m = 0; m < 4; m++)
#pragma unroll
        for (int n = 0; n < 4; n++) {
            acc1[m][n] = (floatx4){0.f, 0.f, 0.f, 0.f};
            acc3[m][n] = (floatx4){0.f, 0.f, 0.f, 0.f};
        }

    for (int kt = 0; kt < 8; kt++) {
        int kb = kt * 32;
        load_lds16(a0p + kb, ldsA0);
        load_lds16(a1p + kb, ldsA1);
        load_lds16(b1p0 + kb, ldsB10);
        load_lds16(b1p1 + kb, ldsB11);
        load_lds16(b3p0 + kb, ldsB30);
        load_lds16(b3p1 + kb, ldsB31);
        __syncthreads();
        short8 af[4], b1f[4], b3f[4];
#pragma unroll
        for (int m = 0; m < 4; m++) af[m] = *(short8*)&sm.s.A[(arowf + m * 16) * 32 + ko];
#pragma unroll
        for (int n = 0; n < 4; n++) {
            b1f[n] = *(short8*)&sm.s.B1[(browf + n * 16) * 32 + ko];
            b3f[n] = *(short8*)&sm.s.B3[(browf + n * 16) * 32 + ko];
        }
#pragma unroll
        for (int m = 0; m < 4; m++)
#pragma unroll
            for (int n = 0; n < 4; n++) {
                acc1[m][n] = __builtin_amdgcn_mfma_f32_16x16x32_bf16(af[m], b1f[n], acc1[m][n], 0, 0, 0);
                acc3[m][n] = __builtin_amdgcn_mfma_f32_16x16x32_bf16(af[m], b3f[n], acc3[m][n], 0, 0, 0);
            }
        __syncthreads();
    }

    // Epilogue: silu(h1)*h3 -> Hs (bf16) -> coalesced 16B stores
#pragma unroll
    for (int m = 0; m < 4; m++)
#pragma unroll
        for (int n = 0; n < 4; n++)
#pragma unroll
            for (int r = 0; r < 4; r++) {
                float h1 = acc1[m][n][r], h3 = acc3[m][n][r];
                float sv = h1 / (1.0f + __expf(-h1)) * h3;
                sm.Hs[(wm * 64 + m * 16 + quad * 4 + r) * 136 + wn * 64 + n * 16 + l15] = f2bf(sv);
            }
    __syncthreads();
#pragma unroll
    for (int it = 0; it < 8; it++) {
        int s = it * 256 + tid;
        int row = s >> 4, c16 = s & 15;
        if (row < mval)
            *(int4*)(h + (size_t)(row0 + row) * H_PAD + c * 128 + c16 * 8) =
                *(int4*)&sm.Hs[row * 136 + c16 * 8];
    }
}

// ---------------- Pass 2: y = h . w2^T (bf16 y, no atomics) ----------------
// Block: 128 rows x 128-col chunk (grid.y = 2); 2x2 waves, each 64x64. K = 768.
__global__ __launch_bounds__(256, 2) void expert_ffn2(
    const unsigned short* __restrict__ h, const unsigned short* __restrict__ w2b,
    const int* __restrict__ offsets, unsigned short* __restrict__ y) {
    int e = blockIdx.x >> 6;
    int mt = blockIdx.x & 63;
    int p = blockIdx.y;  // 0..1 (C chunk)
    int off0 = offsets[e], off1 = offsets[e + 1];
    int row0 = off0 + mt * 128;
    if (row0 >= off1) return;
    int mval = min(128, off1 - row0);

    __shared__ union {
        struct { unsigned short A[128 * 32], B[128 * 32]; } s;
        unsigned short Hs[128 * 136];
    } sm;

    int tid = threadIdx.x, lane = tid & 63, w = tid >> 6;
    int wm = w & 1, wn = w >> 1;
    int ra = tid >> 2;
    int acol = (tid & 3) * 8;
    const unsigned short* ap0 = h + (size_t)(row0 + ra) * H_PAD + acol;
    const unsigned short* ap1 = ap0 + (size_t)64 * H_PAD;
    const unsigned short* bp0 = w2b + ((size_t)e * C_DIM + p * 128 + ra) * H_PAD + acol;
    const unsigned short* bp1 = bp0 + (size_t)64 * H_PAD;

    unsigned short* ldsA0 = sm.s.A + w * 512;
    unsigned short* ldsA1 = sm.s.A + 2048 + w * 512;
    unsigned short* ldsB0 = sm.s.B + w * 512;
    unsigned short* ldsB1 = sm.s.B + 2048 + w * 512;

    floatx4 acc[4][4];
#pragma unroll
    for (int m = 0; m < 4; m++)
#pragma unroll
        for (int n = 0; n < 4; n++) acc[m][n] = (floatx4){0.f, 0.f, 0.f, 0.f};

    int ko = (lane >> 4) * 8;
    int l15 = lane & 15;
    int arowf = wm * 64 + l15;
    int browf = wn * 64 + l15;
    int quad = lane >> 4;

    for (int kt = 0; kt < H_PAD / 32; kt++) {  // 24
        int kb = kt * 32;
        load_lds16(ap0 + kb, ldsA0);
        load_lds16(ap1 + kb, ldsA1);
        load_lds16(bp0 + kb, ldsB0);
        load_lds16(bp1 + kb, ldsB1);
        __syncthreads();
        short8 af[4], bf[4];
#pragma unroll
        for (int m = 0; m < 4; m++) af[m] = *(short8*)&sm.s.A[(arowf + m * 16) * 32 + ko];
#pragma unroll
        for (int n = 0; n < 4; n++) bf[n] = *(short8*)&sm.s.B[(browf + n * 16) * 32 + ko];
#pragma unroll
        for (int m = 0; m < 4; m++)
#pragma unroll
            for (int n = 0; n < 4; n++)
                acc[m][n] = __builtin_amdgcn_mfma_f32_16x16x32_bf16(af[m], bf[n], acc[m][n], 0, 0, 0);
        __syncthreads();
    }

    // Epilogue: y chunk (bf16) via Hs transpose
#pragma unroll
    for (int m = 0; m < 4; m++)
#pragma unroll
        for (int n = 0; n < 4; n++)
#pragma unroll
            for (int r = 0; r < 4; r++)
                sm.Hs[(wm * 64 + m * 16 + quad * 4 + r) * 136 + wn * 64 + n * 16 + l15] =
                    f2bf(acc[m][n][r]);
    __syncthreads();
#pragma unroll
    for (int it = 0; it < 8; it++) {
        int s = it * 256 + tid;
        int row = s >> 4, c16 = s & 15;
        if (row < mval)
            *(int4*)(y + (size_t)(row0 + row) * C_DIM + p * 128 + c16 * 8) =
                *(int4*)&sm.Hs[row * 136 + c16 * 8];
    }
}

// Combine: out[t][:] = g0*y[row(2t)][:] + g1*y[row(2t+1)][:]  (fp32 out)
__global__ __launch_bounds__(256) void combine_kernel(
    const unsigned short* __restrict__ y, const int* __restrict__ as_row,
    const float* __restrict__ as_gate, float* __restrict__ out) {
    int tid = threadIdx.x, lane = tid & 63;
    int t = blockIdx.x * 4 + (tid >> 6);
    int r0 = as_row[2 * t], r1 = as_row[2 * t + 1];
    float g0 = as_gate[2 * t], g1 = as_gate[2 * t + 1];
    uint2 a = *(const uint2*)(y + (size_t)r0 * C_DIM + lane * 4);
    uint2 b = *(const uint2*)(y + (size_t)r1 * C_DIM + lane * 4);
    float4 o;
    o.x = g0 * bf2f((unsigned short)(a.x & 0xffff)) + g1 * bf2f((unsigned short)(b.x & 0xffff));
    o.y = g0 * bf2f((unsigned short)(a.x >> 16)) + g1 * bf2f((unsigned short)(b.x >> 16));
    o.z = g0 * bf2f((unsigned short)(a.y & 0xffff)) + g1 * bf2f((unsigned short)(b.y & 0xffff));
    o.w = g0 * bf2f((unsigned short)(a.y >> 16)) + g1 * bf2f((unsigned short)(b.y >> 16));
    *(float4*)(out + (size_t)t * C_DIM + lane * 4) = o;
}

extern "C" void kernel_launch(void* const* d_in, const int* in_sizes, int n_in,
                              void* d_out, int out_size, void* d_ws, size_t ws_size,
                              hipStream_t stream) {
    const float* x = (const float*)d_in[0];
    const float* rw = (const float*)d_in[1];
    const float* w1 = (const float*)d_in[2];
    const float* w2 = (const float*)d_in[3];
    const float* w3 = (const float*)d_in[4];
    float* out = (float*)d_out;

    char* ws = (char*)d_ws;
    size_t o = 0;
    auto alloc = [&](size_t bytes) {
        void* p = ws + o;
        o = (o + bytes + 255) & ~(size_t)255;
        return p;
    };
    unsigned short* xb = (unsigned short*)alloc((size_t)N_TOK * C_DIM * 2);
    unsigned short* w1b = (unsigned short*)alloc((size_t)E_NUM * H_PAD * C_DIM * 2);
    unsigned short* w3b = (unsigned short*)alloc((size_t)E_NUM * H_PAD * C_DIM * 2);
    unsigned short* w2b = (unsigned short*)alloc((size_t)E_NUM * C_DIM * H_PAD * 2);
    unsigned short* hbuf = (unsigned short*)alloc((size_t)(NROWS + 128) * H_PAD * 2);
    unsigned short* ybuf = (unsigned short*)alloc((size_t)NROWS * C_DIM * 2);
    int* offsets = (int*)alloc((E_NUM + 1) * 4);
    int* as_e = (int*)alloc(NROWS * 4);
    float* as_gate = (float*)alloc(NROWS * 4);
    int* row_token = (int*)alloc(NROWS * 4);
    int* as_row = (int*)alloc(NROWS * 4);
    int* block_hist = (int*)alloc(HB * E_NUM * 4);
    int* block_base = (int*)alloc(HB * E_NUM * 4);

    wconvert<<<(2 * P13 + P2 + 255) / 256, 256, 0, stream>>>(w1, w3, w2, w1b, w3b, w2b);
    router_kernel<<<N_TOK / 4, 256, 0, stream>>>(x, rw, xb, as_e, as_gate);
    hist_kernel<<<HB, 256, 0, stream>>>(as_e, block_hist);
    scan2_kernel<<<1, 64, 0, stream>>>(block_hist, offsets, block_base);
    scatter_kernel<<<HB, 256, 0, stream>>>(as_e, block_base, row_token, as_row);

    expert_ffn1<<<dim3(E_NUM * 64, 6), 256, 0, stream>>>(xb, w1b, w3b, offsets, row_token, hbuf);
    expert_ffn2<<<dim3(E_NUM * 64, 2), 256, 0, stream>>>(hbuf, w2b, offsets, ybuf);
    combine_kernel<<<N_TOK / 4, 256, 0, stream>>>(ybuf, as_row, as_gate, out);
}

// Round 8
// 198.743 us; speedup vs baseline: 3.0446x; 1.0443x over previous
//
#include <hip/hip_runtime.h>
#include <hip/hip_bf16.h>

#define N_TOK 16384
#define C_DIM 256
#define E_NUM 8
#define H_DIM 682
#define H_PAD 768          // 6 * 128 (pad rows/cols are exact zeros)
#define NROWS (N_TOK * 2)  // total expert-assignments (top-2)
#define HB 64              // histogram/scatter blocks
#define APB (NROWS / HB)   // assignments per block = 512

typedef short short8 __attribute__((ext_vector_type(8)));
typedef float floatx4 __attribute__((ext_vector_type(4)));
typedef unsigned int uint;

__device__ inline unsigned short f2bf(float v) {
    union { float f; uint u; } x; x.f = v;
    uint r = (x.u + 0x7fffu + ((x.u >> 16) & 1u)) >> 16;
    return (unsigned short)r;
}
__device__ inline float bf2f(unsigned short v) {
    union { uint u; float f; } x; x.u = ((uint)v) << 16; return x.f;
}

// Async global->LDS 16B/lane. LDS dst: wave-uniform base + lane*16.
__device__ __forceinline__ void load_lds16(const void* g, void* l) {
    __builtin_amdgcn_global_load_lds(
        (const __attribute__((address_space(1))) unsigned int*)g,
        (__attribute__((address_space(3))) unsigned int*)l, 16, 0, 0);
}

// Fused weight convert: w1,w3 [E][682][256] -> [E][768][256] bf16 (zero pad rows);
// w2 [E][256][682] -> [E][256][768] bf16 (zero pad cols). Pair-granular (uint writes).
#define P13 (E_NUM * H_PAD * (C_DIM / 2))
#define P2  (E_NUM * C_DIM * (H_PAD / 2))
__global__ void wconvert(const float* __restrict__ w1, const float* __restrict__ w3,
                         const float* __restrict__ w2, unsigned short* __restrict__ w1b,
                         unsigned short* __restrict__ w3b, unsigned short* __restrict__ w2b) {
    int idx = blockIdx.x * 256 + threadIdx.x;
    if (idx < 2 * P13) {
        const float* src = (idx < P13) ? w1 : w3;
        unsigned short* dst = (idx < P13) ? w1b : w3b;
        int i = (idx < P13) ? idx : idx - P13;
        int e = i / (H_PAD * (C_DIM / 2));
        int rem = i - e * (H_PAD * (C_DIM / 2));
        int r = rem / (C_DIM / 2);
        int c2 = rem - r * (C_DIM / 2);
        uint v = 0;
        if (r < H_DIM) {
            const float2 f = *(const float2*)(src + ((size_t)e * H_DIM + r) * C_DIM + c2 * 2);
            v = (uint)f2bf(f.x) | ((uint)f2bf(f.y) << 16);
        }
        ((uint*)dst)[i] = v;
    } else if (idx < 2 * P13 + P2) {
        int i = idx - 2 * P13;
        int e = i / (C_DIM * (H_PAD / 2));
        int rem = i - e * (C_DIM * (H_PAD / 2));
        int r = rem / (H_PAD / 2);
        int c2 = rem - r * (H_PAD / 2);
        uint v = 0;
        if (c2 * 2 < H_DIM) {  // H_DIM even -> clean pair boundary
            const float2 f = *(const float2*)(w2 + ((size_t)e * C_DIM + r) * H_DIM + c2 * 2);
            v = (uint)f2bf(f.x) | ((uint)f2bf(f.y) << 16);
        }
        ((uint*)w2b)[i] = v;
    }
}

// fp32 router (one wave/token): logits -> softmax -> top2 -> renorm gates.
// Also emits xb = bf16(x) (fused convert; x is already being read here).
__global__ __launch_bounds__(256) void router_kernel(
    const float* __restrict__ x, const float* __restrict__ rw,
    unsigned short* __restrict__ xb, int* __restrict__ as_e, float* __restrict__ as_gate) {
    __shared__ float rws[E_NUM * C_DIM];
    int tid = threadIdx.x;
    for (int i = tid; i < E_NUM * C_DIM; i += 256) rws[i] = rw[i];
    __syncthreads();
    int wave = tid >> 6, lane = tid & 63;
    int t = blockIdx.x * 4 + wave;
    const float4 xv = *(const float4*)(x + (size_t)t * C_DIM + lane * 4);
    uint2 pk;
    pk.x = (uint)f2bf(xv.x) | ((uint)f2bf(xv.y) << 16);
    pk.y = (uint)f2bf(xv.z) | ((uint)f2bf(xv.w) << 16);
    *(uint2*)(xb + (size_t)t * C_DIM + lane * 4) = pk;
    float p[E_NUM];
#pragma unroll
    for (int e = 0; e < E_NUM; e++) {
        const float* wr = &rws[e * C_DIM + lane * 4];
        p[e] = xv.x * wr[0] + xv.y * wr[1] + xv.z * wr[2] + xv.w * wr[3];
    }
#pragma unroll
    for (int off = 32; off >= 1; off >>= 1) {
#pragma unroll
        for (int e = 0; e < E_NUM; e++) p[e] += __shfl_down(p[e], off, 64);
    }
    if (lane == 0) {
        float m = p[0];
#pragma unroll
        for (int e = 1; e < E_NUM; e++) m = fmaxf(m, p[e]);
        float s = 0.f, q[E_NUM];
#pragma unroll
        for (int e = 0; e < E_NUM; e++) { q[e] = expf(p[e] - m); s += q[e]; }
#pragma unroll
        for (int e = 0; e < E_NUM; e++) q[e] /= s;
        int e0 = 0;
#pragma unroll
        for (int e = 1; e < E_NUM; e++) if (q[e] > q[e0]) e0 = e;
        int e1 = (e0 == 0) ? 1 : 0;
#pragma unroll
        for (int e = 0; e < E_NUM; e++) {
            if (e != e0 && q[e] > q[e1]) e1 = e;
        }
        float g0 = q[e0], g1 = q[e1];
        float denom = g0 + g1 + 1e-9f;
        g0 /= denom; g1 /= denom;
        as_e[t * 2] = e0; as_gate[t * 2] = g0;
        as_e[t * 2 + 1] = e1; as_gate[t * 2 + 1] = g1;
    }
}

// Per-block expert histogram (LDS atomics), 64 blocks x 512 assignments.
__global__ __launch_bounds__(256) void hist_kernel(const int* __restrict__ as_e,
                                                   int* __restrict__ block_hist) {
    __shared__ int lh[E_NUM];
    int b = blockIdx.x, tid = threadIdx.x;
    if (tid < E_NUM) lh[tid] = 0;
    __syncthreads();
    for (int i = tid; i < APB; i += 256) atomicAdd(&lh[as_e[b * APB + i]], 1);
    __syncthreads();
    if (tid < E_NUM) block_hist[b * E_NUM + tid] = lh[tid];
}

// Scan: expert totals -> offsets[9]; per-(block,expert) base cursors.
__global__ void scan2_kernel(const int* __restrict__ block_hist, int* __restrict__ offsets,
                             int* __restrict__ block_base) {
    __shared__ int tot[E_NUM], off[E_NUM];
    int e = threadIdx.x;
    if (e < E_NUM) {
        int s = 0;
        for (int b = 0; b < HB; b++) s += block_hist[b * E_NUM + e];
        tot[e] = s;
    }
    __syncthreads();
    if (e == 0) {
        int acc = 0;
        for (int i = 0; i < E_NUM; i++) { off[i] = acc; offsets[i] = acc; acc += tot[i]; }
        offsets[E_NUM] = acc;
    }
    __syncthreads();
    if (e < E_NUM) {
        int acc = off[e];
        for (int b = 0; b < HB; b++) { block_base[b * E_NUM + e] = acc; acc += block_hist[b * E_NUM + e]; }
    }
}

// Scatter: row_token (expert-sorted) + inverse map as_row[a] = row.
__global__ __launch_bounds__(256) void scatter_kernel(
    const int* __restrict__ as_e, const int* __restrict__ block_base,
    int* __restrict__ row_token, int* __restrict__ as_row) {
    __shared__ int cur[E_NUM];
    int b = blockIdx.x, tid = threadIdx.x;
    if (tid < E_NUM) cur[tid] = block_base[b * E_NUM + tid];
    __syncthreads();
    for (int i = tid; i < APB; i += 256) {
        int a = b * APB + i;
        int e = as_e[a];
        int p = atomicAdd(&cur[e], 1);
        row_token[p] = a >> 1;
        as_row[a] = p;
    }
}

// ---------------- Pass 1: h = silu(x.w1^T) * (x.w3^T) ----------------
// Block: 128 rows x ONE 128-col chunk (grid.y = 6); 2x2 waves, each 64x64.
// Double-buffered LDS staging: stage(kt+1) issued before compute(kt).
__global__ __launch_bounds__(256, 2) void expert_ffn1(
    const unsigned short* __restrict__ xb, const unsigned short* __restrict__ w1b,
    const unsigned short* __restrict__ w3b, const int* __restrict__ offsets,
    const int* __restrict__ row_token, unsigned short* __restrict__ h) {
    int e = blockIdx.x >> 6;
    int mt = blockIdx.x & 63;
    int c = blockIdx.y;  // 0..5
    int off0 = offsets[e], off1 = offsets[e + 1];
    int row0 = off0 + mt * 128;
    if (row0 >= off1) return;
    int mval = min(128, off1 - row0);

    // Per stage: A(128x32)=4096 B1=4096 B3=4096 shorts -> 24 KB; x2 = 48 KB.
    __shared__ union {
        unsigned short buf[2][12288];
        unsigned short Hs[128 * 136];  // 34816 B (overlaps both buffers)
    } sm;

    int tid = threadIdx.x, lane = tid & 63, w = tid >> 6;
    int wm = w & 1, wn = w >> 1;
    int ra = tid >> 2;             // staging row (round 0); +64 for round 1
    int acol = (tid & 3) * 8;      // 16B chunk within 32-col k-tile
    int tok0 = row_token[row0 + min(ra, mval - 1)];
    int tok1 = row_token[row0 + min(ra + 64, mval - 1)];
    const unsigned short* a0p = xb + (size_t)tok0 * C_DIM + acol;
    const unsigned short* a1p = xb + (size_t)tok1 * C_DIM + acol;
    const unsigned short* b1p0 = w1b + ((size_t)e * H_PAD + c * 128 + ra) * C_DIM + acol;
    const unsigned short* b1p1 = b1p0 + (size_t)64 * C_DIM;
    const unsigned short* b3p0 = w3b + ((size_t)e * H_PAD + c * 128 + ra) * C_DIM + acol;
    const unsigned short* b3p1 = b3p0 + (size_t)64 * C_DIM;

    int wofs = w * 512;
    auto stage = [&](int kt, int s) {
        int kb = kt * 32;
        unsigned short* base = sm.buf[s];
        load_lds16(a0p + kb, base + wofs);
        load_lds16(a1p + kb, base + 2048 + wofs);
        load_lds16(b1p0 + kb, base + 4096 + wofs);
        load_lds16(b1p1 + kb, base + 6144 + wofs);
        load_lds16(b3p0 + kb, base + 8192 + wofs);
        load_lds16(b3p1 + kb, base + 10240 + wofs);
    };

    int ko = (lane >> 4) * 8;
    int l15 = lane & 15;
    int arowf = wm * 64 + l15;
    int browf = wn * 64 + l15;
    int quad = lane >> 4;

    stage(0, 0);  // in flight during acc init

    floatx4 acc1[4][4], acc3[4][4];
#pragma unroll
    for (int m = 0; m < 4; m++)
#pragma unroll
        for (int n = 0; n < 4; n++) {
            acc1[m][n] = (floatx4){0.f, 0.f, 0.f, 0.f};
            acc3[m][n] = (floatx4){0.f, 0.f, 0.f, 0.f};
        }

    for (int kt = 0; kt < 8; kt++) {
        __syncthreads();           // drains stage(kt); all waves done reading other buf
        if (kt + 1 < 8) stage(kt + 1, (kt + 1) & 1);  // in flight during compute(kt)
        const unsigned short* cur = sm.buf[kt & 1];
        short8 af[4], b1f[4], b3f[4];
#pragma unroll
        for (int m = 0; m < 4; m++) af[m] = *(short8*)&cur[(arowf + m * 16) * 32 + ko];
#pragma unroll
        for (int n = 0; n < 4; n++) {
            b1f[n] = *(short8*)&cur[4096 + (browf + n * 16) * 32 + ko];
            b3f[n] = *(short8*)&cur[8192 + (browf + n * 16) * 32 + ko];
        }
#pragma unroll
        for (int m = 0; m < 4; m++)
#pragma unroll
            for (int n = 0; n < 4; n++) {
                acc1[m][n] = __builtin_amdgcn_mfma_f32_16x16x32_bf16(af[m], b1f[n], acc1[m][n], 0, 0, 0);
                acc3[m][n] = __builtin_amdgcn_mfma_f32_16x16x32_bf16(af[m], b3f[n], acc3[m][n], 0, 0, 0);
            }
    }
    __syncthreads();  // all compute done before Hs overwrites buffers

    // Epilogue: silu(h1)*h3 -> Hs (bf16) -> coalesced 16B stores
#pragma unroll
    for (int m = 0; m < 4; m++)
#pragma unroll
        for (int n = 0; n < 4; n++)
#pragma unroll
            for (int r = 0; r < 4; r++) {
                float h1 = acc1[m][n][r], h3 = acc3[m][n][r];
                float sv = h1 / (1.0f + __expf(-h1)) * h3;
                sm.Hs[(wm * 64 + m * 16 + quad * 4 + r) * 136 + wn * 64 + n * 16 + l15] = f2bf(sv);
            }
    __syncthreads();
#pragma unroll
    for (int it = 0; it < 8; it++) {
        int s = it * 256 + tid;
        int row = s >> 4, c16 = s & 15;
        if (row < mval)
            *(int4*)(h + (size_t)(row0 + row) * H_PAD + c * 128 + c16 * 8) =
                *(int4*)&sm.Hs[row * 136 + c16 * 8];
    }
}

// ---------------- Pass 2: y = h . w2^T (bf16 y, no atomics) ----------------
// Block: 128 rows x 128-col chunk (grid.y = 2); 2x2 waves, each 64x64. K = 768.
// Double-buffered LDS staging.
__global__ __launch_bounds__(256, 2) void expert_ffn2(
    const unsigned short* __restrict__ h, const unsigned short* __restrict__ w2b,
    const int* __restrict__ offsets, unsigned short* __restrict__ y) {
    int e = blockIdx.x >> 6;
    int mt = blockIdx.x & 63;
    int p = blockIdx.y;  // 0..1 (C chunk)
    int off0 = offsets[e], off1 = offsets[e + 1];
    int row0 = off0 + mt * 128;
    if (row0 >= off1) return;
    int mval = min(128, off1 - row0);

    // Per stage: A(128x32)=4096 B(128x32)=4096 shorts -> 16 KB; x2 = 32 KB.
    __shared__ union {
        unsigned short buf[2][8192];
        unsigned short Hs[128 * 136];  // 34816 B
    } sm;

    int tid = threadIdx.x, lane = tid & 63, w = tid >> 6;
    int wm = w & 1, wn = w >> 1;
    int ra = tid >> 2;
    int acol = (tid & 3) * 8;
    const unsigned short* ap0 = h + (size_t)(row0 + ra) * H_PAD + acol;
    const unsigned short* ap1 = ap0 + (size_t)64 * H_PAD;
    const unsigned short* bp0 = w2b + ((size_t)e * C_DIM + p * 128 + ra) * H_PAD + acol;
    const unsigned short* bp1 = bp0 + (size_t)64 * H_PAD;

    int wofs = w * 512;
    auto stage = [&](int kt, int s) {
        int kb = kt * 32;
        unsigned short* base = sm.buf[s];
        load_lds16(ap0 + kb, base + wofs);
        load_lds16(ap1 + kb, base + 2048 + wofs);
        load_lds16(bp0 + kb, base + 4096 + wofs);
        load_lds16(bp1 + kb, base + 6144 + wofs);
    };

    int ko = (lane >> 4) * 8;
    int l15 = lane & 15;
    int arowf = wm * 64 + l15;
    int browf = wn * 64 + l15;
    int quad = lane >> 4;

    stage(0, 0);

    floatx4 acc[4][4];
#pragma unroll
    for (int m = 0; m < 4; m++)
#pragma unroll
        for (int n = 0; n < 4; n++) acc[m][n] = (floatx4){0.f, 0.f, 0.f, 0.f};

    for (int kt = 0; kt < H_PAD / 32; kt++) {  // 24
        __syncthreads();
        if (kt + 1 < H_PAD / 32) stage(kt + 1, (kt + 1) & 1);
        const unsigned short* cur = sm.buf[kt & 1];
        short8 af[4], bf[4];
#pragma unroll
        for (int m = 0; m < 4; m++) af[m] = *(short8*)&cur[(arowf + m * 16) * 32 + ko];
#pragma unroll
        for (int n = 0; n < 4; n++) bf[n] = *(short8*)&cur[4096 + (browf + n * 16) * 32 + ko];
#pragma unroll
        for (int m = 0; m < 4; m++)
#pragma unroll
            for (int n = 0; n < 4; n++)
                acc[m][n] = __builtin_amdgcn_mfma_f32_16x16x32_bf16(af[m], bf[n], acc[m][n], 0, 0, 0);
    }
    __syncthreads();

    // Epilogue: y chunk (bf16) via Hs transpose
#pragma unroll
    for (int m = 0; m < 4; m++)
#pragma unroll
        for (int n = 0; n < 4; n++)
#pragma unroll
            for (int r = 0; r < 4; r++)
                sm.Hs[(wm * 64 + m * 16 + quad * 4 + r) * 136 + wn * 64 + n * 16 + l15] =
                    f2bf(acc[m][n][r]);
    __syncthreads();
#pragma unroll
    for (int it = 0; it < 8; it++) {
        int s = it * 256 + tid;
        int row = s >> 4, c16 = s & 15;
        if (row < mval)
            *(int4*)(y + (size_t)(row0 + row) * C_DIM + p * 128 + c16 * 8) =
                *(int4*)&sm.Hs[row * 136 + c16 * 8];
    }
}

// Combine: out[t][:] = g0*y[row(2t)][:] + g1*y[row(2t+1)][:]  (fp32 out)
__global__ __launch_bounds__(256) void combine_kernel(
    const unsigned short* __restrict__ y, const int* __restrict__ as_row,
    const float* __restrict__ as_gate, float* __restrict__ out) {
    int tid = threadIdx.x, lane = tid & 63;
    int t = blockIdx.x * 4 + (tid >> 6);
    int r0 = as_row[2 * t], r1 = as_row[2 * t + 1];
    float g0 = as_gate[2 * t], g1 = as_gate[2 * t + 1];
    uint2 a = *(const uint2*)(y + (size_t)r0 * C_DIM + lane * 4);
    uint2 b = *(const uint2*)(y + (size_t)r1 * C_DIM + lane * 4);
    float4 o;
    o.x = g0 * bf2f((unsigned short)(a.x & 0xffff)) + g1 * bf2f((unsigned short)(b.x & 0xffff));
    o.y = g0 * bf2f((unsigned short)(a.x >> 16)) + g1 * bf2f((unsigned short)(b.x >> 16));
    o.z = g0 * bf2f((unsigned short)(a.y & 0xffff)) + g1 * bf2f((unsigned short)(b.y & 0xffff));
    o.w = g0 * bf2f((unsigned short)(a.y >> 16)) + g1 * bf2f((unsigned short)(b.y >> 16));
    *(float4*)(out + (size_t)t * C_DIM + lane * 4) = o;
}

extern "C" void kernel_launch(void* const* d_in, const int* in_sizes, int n_in,
                              void* d_out, int out_size, void* d_ws, size_t ws_size,
                              hipStream_t stream) {
    const float* x = (const float*)d_in[0];
    const float* rw = (const float*)d_in[1];
    const float* w1 = (const float*)d_in[2];
    const float* w2 = (const float*)d_in[3];
    const float* w3 = (const float*)d_in[4];
    float* out = (float*)d_out;

    char* ws = (char*)d_ws;
    size_t o = 0;
    auto alloc = [&](size_t bytes) {
        void* p = ws + o;
        o = (o + bytes + 255) & ~(size_t)255;
        return p;
    };
    unsigned short* xb = (unsigned short*)alloc((size_t)N_TOK * C_DIM * 2);
    unsigned short* w1b = (unsigned short*)alloc((size_t)E_NUM * H_PAD * C_DIM * 2);
    unsigned short* w3b = (unsigned short*)alloc((size_t)E_NUM * H_PAD * C_DIM * 2);
    unsigned short* w2b = (unsigned short*)alloc((size_t)E_NUM * C_DIM * H_PAD * 2);
    unsigned short* hbuf = (unsigned short*)alloc((size_t)(NROWS + 128) * H_PAD * 2);
    unsigned short* ybuf = (unsigned short*)alloc((size_t)NROWS * C_DIM * 2);
    int* offsets = (int*)alloc((E_NUM + 1) * 4);
    int* as_e = (int*)alloc(NROWS * 4);
    float* as_gate = (float*)alloc(NROWS * 4);
    int* row_token = (int*)alloc(NROWS * 4);
    int* as_row = (int*)alloc(NROWS * 4);
    int* block_hist = (int*)alloc(HB * E_NUM * 4);
    int* block_base = (int*)alloc(HB * E_NUM * 4);

    wconvert<<<(2 * P13 + P2 + 255) / 256, 256, 0, stream>>>(w1, w3, w2, w1b, w3b, w2b);
    router_kernel<<<N_TOK / 4, 256, 0, stream>>>(x, rw, xb, as_e, as_gate);
    hist_kernel<<<HB, 256, 0, stream>>>(as_e, block_hist);
    scan2_kernel<<<1, 64, 0, stream>>>(block_hist, offsets, block_base);
    scatter_kernel<<<HB, 256, 0, stream>>>(as_e, block_base, row_token, as_row);

    expert_ffn1<<<dim3(E_NUM * 64, 6), 256, 0, stream>>>(xb, w1b, w3b, offsets, row_token, hbuf);
    expert_ffn2<<<dim3(E_NUM * 64, 2), 256, 0, stream>>>(hbuf, w2b, offsets, ybuf);
    combine_kernel<<<N_TOK / 4, 256, 0, stream>>>(ybuf, as_row, as_gate, out);
}